// Round 1
// baseline (1476.468 us; speedup 1.0000x reference)
//
#include <hip/hip_runtime.h>
#include <hip/hip_bf16.h>
#include <cstdint>
#include <cstddef>

#define NFEAT 512
#define H2 256
#define H3 256
#define H4 128
#define NCLASS 16

// ---------------- CSR build ----------------
__global__ void k_hist(const int* __restrict__ er, int* __restrict__ cnt, int E) {
    for (int e = blockIdx.x * blockDim.x + threadIdx.x; e < E; e += gridDim.x * blockDim.x)
        atomicAdd(&cnt[er[e]], 1);
}

// block-wise exclusive scan (256/block), Hillis-Steele
__global__ void k_scan1(const int* __restrict__ cnt, int* __restrict__ ex,
                        int* __restrict__ bsum, int n) {
    __shared__ int s[256];
    int i = blockIdx.x * 256 + threadIdx.x;
    int v = (i < n) ? cnt[i] : 0;
    s[threadIdx.x] = v;
    __syncthreads();
    #pragma unroll
    for (int off = 1; off < 256; off <<= 1) {
        int t = (threadIdx.x >= (unsigned)off) ? s[threadIdx.x - off] : 0;
        __syncthreads();
        s[threadIdx.x] += t;
        __syncthreads();
    }
    if (i < n) ex[i] = s[threadIdx.x] - v;            // exclusive within block
    if (threadIdx.x == 255) bsum[blockIdx.x] = s[255]; // block total
}

__global__ void k_scan2(int* __restrict__ bsum, int nb) {
    __shared__ int s[512];
    int v = ((int)threadIdx.x < nb) ? bsum[threadIdx.x] : 0;
    s[threadIdx.x] = v;
    __syncthreads();
    #pragma unroll
    for (int off = 1; off < 512; off <<= 1) {
        int t = (threadIdx.x >= (unsigned)off) ? s[threadIdx.x - off] : 0;
        __syncthreads();
        s[threadIdx.x] += t;
        __syncthreads();
    }
    if ((int)threadIdx.x < nb) bsum[threadIdx.x] = s[threadIdx.x] - v; // exclusive
}

__global__ void k_scan3(int* __restrict__ rp, int* __restrict__ ofs,
                        const int* __restrict__ bsum, const int* __restrict__ cnt,
                        int n) {
    int i = blockIdx.x * 256 + threadIdx.x;
    if (i < n) {
        int v = rp[i] + bsum[blockIdx.x];
        rp[i] = v;
        ofs[i] = v;
        if (i == n - 1) rp[n] = v + cnt[i]; // == E
    }
}

__global__ void k_scatter(const int* __restrict__ er, const int* __restrict__ ec,
                          const float* __restrict__ ev, int* __restrict__ ofs,
                          int* __restrict__ cs, float* __restrict__ vs, int E) {
    for (int e = blockIdx.x * blockDim.x + threadIdx.x; e < E; e += gridDim.x * blockDim.x) {
        int r = er[e];
        int p = atomicAdd(&ofs[r], 1);
        cs[p] = ec[e];
        vs[p] = ev[e];
    }
}

// ---------------- fp32 GEMM: C[N,M] = A[N,K] @ B[K,M] ----------------
// BM=BN=64, BK=16, 256 threads, 4x4 per thread
__global__ __launch_bounds__(256) void k_gemm(const float* __restrict__ A,
                                              const float* __restrict__ B,
                                              float* __restrict__ C,
                                              int N, int K, int M) {
    __shared__ float As[16][65]; // [k][row], +1 pad kills write conflicts
    __shared__ float Bs[16][64]; // [k][col]
    int tid = threadIdx.x;
    int tx = tid & 15, ty = tid >> 4;
    int row0 = blockIdx.y * 64, col0 = blockIdx.x * 64;
    int arow = tid >> 2, acol = (tid & 3) << 2;   // 64 rows x 16 k, float4 per thread
    int brow = tid >> 4, bcol = (tid & 15) << 2;  // 16 k x 64 cols, float4 per thread
    float c[4][4] = {};

    for (int k0 = 0; k0 < K; k0 += 16) {
        int gr = row0 + arow;
        float4 av = make_float4(0.f, 0.f, 0.f, 0.f);
        if (gr < N) av = *(const float4*)&A[(size_t)gr * K + k0 + acol];
        As[acol + 0][arow] = av.x;
        As[acol + 1][arow] = av.y;
        As[acol + 2][arow] = av.z;
        As[acol + 3][arow] = av.w;
        float4 bv = *(const float4*)&B[(size_t)(k0 + brow) * M + col0 + bcol];
        *(float4*)&Bs[brow][bcol] = bv;
        __syncthreads();
        #pragma unroll
        for (int k = 0; k < 16; ++k) {
            float a0 = As[k][ty * 4 + 0];
            float a1 = As[k][ty * 4 + 1];
            float a2 = As[k][ty * 4 + 2];
            float a3 = As[k][ty * 4 + 3];
            float4 b = *(const float4*)&Bs[k][tx * 4];
            c[0][0] = fmaf(a0, b.x, c[0][0]); c[0][1] = fmaf(a0, b.y, c[0][1]);
            c[0][2] = fmaf(a0, b.z, c[0][2]); c[0][3] = fmaf(a0, b.w, c[0][3]);
            c[1][0] = fmaf(a1, b.x, c[1][0]); c[1][1] = fmaf(a1, b.y, c[1][1]);
            c[1][2] = fmaf(a1, b.z, c[1][2]); c[1][3] = fmaf(a1, b.w, c[1][3]);
            c[2][0] = fmaf(a2, b.x, c[2][0]); c[2][1] = fmaf(a2, b.y, c[2][1]);
            c[2][2] = fmaf(a2, b.z, c[2][2]); c[2][3] = fmaf(a2, b.w, c[2][3]);
            c[3][0] = fmaf(a3, b.x, c[3][0]); c[3][1] = fmaf(a3, b.y, c[3][1]);
            c[3][2] = fmaf(a3, b.z, c[3][2]); c[3][3] = fmaf(a3, b.w, c[3][3]);
        }
        __syncthreads();
    }
    #pragma unroll
    for (int i = 0; i < 4; ++i) {
        int gr = row0 + ty * 4 + i;
        if (gr < N)
            *(float4*)&C[(size_t)gr * M + col0 + tx * 4] =
                make_float4(c[i][0], c[i][1], c[i][2], c[i][3]);
    }
}

// ---------------- SpMM (CSR) + bias + relu: out[r,f] = relu(sum val*in[col,f] + b[f]) ----------------
template <int F>
__global__ void k_spmm_bias_relu(const int* __restrict__ rp, const int* __restrict__ cs,
                                 const float* __restrict__ vs, const float* __restrict__ in,
                                 const float* __restrict__ bias, float* __restrict__ out,
                                 int N) {
    __shared__ int sc[128];
    __shared__ float sv[128];
    int r = blockIdx.x;
    int e0 = rp[r], e1 = rp[r + 1];
    float acc = 0.f;
    for (int base = e0; base < e1; base += 128) {
        int m = min(128, e1 - base);
        if ((int)threadIdx.x < m) {
            sc[threadIdx.x] = cs[base + threadIdx.x];
            sv[threadIdx.x] = vs[base + threadIdx.x];
        }
        __syncthreads();
        int j = 0;
        for (; j + 4 <= m; j += 4) {
            float x0 = in[(size_t)sc[j + 0] * F + threadIdx.x];
            float x1 = in[(size_t)sc[j + 1] * F + threadIdx.x];
            float x2 = in[(size_t)sc[j + 2] * F + threadIdx.x];
            float x3 = in[(size_t)sc[j + 3] * F + threadIdx.x];
            acc = fmaf(sv[j + 0], x0, acc);
            acc = fmaf(sv[j + 1], x1, acc);
            acc = fmaf(sv[j + 2], x2, acc);
            acc = fmaf(sv[j + 3], x3, acc);
        }
        for (; j < m; ++j)
            acc = fmaf(sv[j], in[(size_t)cs ? (size_t)sc[j] * F + threadIdx.x : 0], acc);
        __syncthreads();
    }
    out[(size_t)r * F + threadIdx.x] = fmaxf(acc + bias[threadIdx.x], 0.f);
}

// ---------------- final dense: out[N,16] = H[N,128] @ Wd[128,16] + bd ----------------
__global__ void k_dense(const float* __restrict__ H, const float* __restrict__ Wd,
                        const float* __restrict__ bd, float* __restrict__ out, int N) {
    __shared__ float Ws[H4 * NCLASS];
    for (int i = threadIdx.x; i < H4 * NCLASS; i += blockDim.x) Ws[i] = Wd[i];
    __syncthreads();
    int gid = blockIdx.x * blockDim.x + threadIdx.x;
    if (gid >= N * NCLASS) return;
    int n = gid >> 4, c = gid & 15;
    const float* h = H + (size_t)n * H4;
    float acc = bd[c];
    #pragma unroll 8
    for (int k = 0; k < H4; ++k) acc = fmaf(h[k], Ws[k * NCLASS + c], acc);
    out[gid] = acc;
}

extern "C" void kernel_launch(void* const* d_in, const int* in_sizes, int n_in,
                              void* d_out, int out_size, void* d_ws, size_t ws_size,
                              hipStream_t stream) {
    const float* x  = (const float*)d_in[0];
    const int*   er = (const int*)d_in[1];
    const int*   ec = (const int*)d_in[2];
    const float* ev = (const float*)d_in[3];
    const float* W1 = (const float*)d_in[4];
    const float* b1 = (const float*)d_in[5];
    const float* W2 = (const float*)d_in[6];
    const float* b2 = (const float*)d_in[7];
    const float* W3 = (const float*)d_in[8];
    const float* b3 = (const float*)d_in[9];
    const float* Wd = (const float*)d_in[10];
    const float* bd = (const float*)d_in[11];
    float* out = (float*)d_out;

    int N = in_sizes[0] / NFEAT;
    int E = in_sizes[1];

    char* w = (char*)d_ws;
    float* tmpA = (float*)w; w += (size_t)N * 256 * 4;
    float* tmpB = (float*)w; w += (size_t)N * 256 * 4;
    int* cnt  = (int*)w; w += (size_t)N * 4;
    int* rp   = (int*)w; w += (size_t)(N + 1) * 4 + 12; // keep following 16B-ish aligned
    int* ofs  = (int*)w; w += (size_t)N * 4;
    int* cs   = (int*)w; w += (size_t)E * 4;
    float* vs = (float*)w; w += (size_t)E * 4;
    int* bsum = (int*)w; w += 4096;

    int nb = (N + 255) / 256; // 391 <= 512

    hipMemsetAsync(cnt, 0, (size_t)N * 4, stream);
    k_hist<<<1024, 256, 0, stream>>>(er, cnt, E);
    k_scan1<<<nb, 256, 0, stream>>>(cnt, rp, bsum, N);
    k_scan2<<<1, 512, 0, stream>>>(bsum, nb);
    k_scan3<<<nb, 256, 0, stream>>>(rp, ofs, bsum, cnt, N);
    k_scatter<<<1024, 256, 0, stream>>>(er, ec, ev, ofs, cs, vs, E);

    dim3 g1(H2 / 64, (N + 63) / 64);
    k_gemm<<<g1, 256, 0, stream>>>(x, W1, tmpA, N, NFEAT, H2);
    k_spmm_bias_relu<256><<<N, 256, 0, stream>>>(rp, cs, vs, tmpA, b1, tmpB, N);

    k_gemm<<<g1, 256, 0, stream>>>(tmpB, W2, tmpA, N, H2, H3);
    k_spmm_bias_relu<256><<<N, 256, 0, stream>>>(rp, cs, vs, tmpA, b2, tmpB, N);

    dim3 g3(H4 / 64, (N + 63) / 64);
    k_gemm<<<g3, 256, 0, stream>>>(tmpB, W3, tmpA, N, H3, H4);
    k_spmm_bias_relu<128><<<N, 128, 0, stream>>>(rp, cs, vs, tmpA, b3, tmpB, N);

    k_dense<<<(N * NCLASS + 255) / 256, 256, 0, stream>>>(tmpB, Wd, bd, out, N);
}

// Round 2
// 1338.328 us; speedup vs baseline: 1.1032x; 1.1032x over previous
//
#include <hip/hip_runtime.h>
#include <hip/hip_bf16.h>
#include <cstdint>
#include <cstddef>

#define NFEAT 512
#define H2 256
#define H3 256
#define H4 128
#define NCLASS 16

typedef __attribute__((ext_vector_type(8))) short short8;
typedef __attribute__((ext_vector_type(4))) float f32x4;

__device__ inline unsigned short f2bf_rne(float x) {
    unsigned int u = __builtin_bit_cast(unsigned int, x);
    unsigned int r = (u + 0x7FFFu + ((u >> 16) & 1u)) >> 16;
    return (unsigned short)r;
}
__device__ inline float bf2f(unsigned short h) {
    return __builtin_bit_cast(float, (unsigned int)h << 16);
}

// ---------------- CSR build ----------------
__global__ void k_hist(const int* __restrict__ er, int* __restrict__ cnt, int E) {
    for (int e = blockIdx.x * blockDim.x + threadIdx.x; e < E; e += gridDim.x * blockDim.x)
        atomicAdd(&cnt[er[e]], 1);
}

__global__ void k_scan1(const int* __restrict__ cnt, int* __restrict__ ex,
                        int* __restrict__ bsum, int n) {
    __shared__ int s[256];
    int i = blockIdx.x * 256 + threadIdx.x;
    int v = (i < n) ? cnt[i] : 0;
    s[threadIdx.x] = v;
    __syncthreads();
    #pragma unroll
    for (int off = 1; off < 256; off <<= 1) {
        int t = (threadIdx.x >= (unsigned)off) ? s[threadIdx.x - off] : 0;
        __syncthreads();
        s[threadIdx.x] += t;
        __syncthreads();
    }
    if (i < n) ex[i] = s[threadIdx.x] - v;
    if (threadIdx.x == 255) bsum[blockIdx.x] = s[255];
}

__global__ void k_scan2(int* __restrict__ bsum, int nb) {
    __shared__ int s[512];
    int v = ((int)threadIdx.x < nb) ? bsum[threadIdx.x] : 0;
    s[threadIdx.x] = v;
    __syncthreads();
    #pragma unroll
    for (int off = 1; off < 512; off <<= 1) {
        int t = (threadIdx.x >= (unsigned)off) ? s[threadIdx.x - off] : 0;
        __syncthreads();
        s[threadIdx.x] += t;
        __syncthreads();
    }
    if ((int)threadIdx.x < nb) bsum[threadIdx.x] = s[threadIdx.x] - v;
}

__global__ void k_scan3(int* __restrict__ rp, int* __restrict__ ofs,
                        const int* __restrict__ bsum, const int* __restrict__ cnt,
                        int n) {
    int i = blockIdx.x * 256 + threadIdx.x;
    if (i < n) {
        int v = rp[i] + bsum[blockIdx.x];
        rp[i] = v;
        ofs[i] = v;
        if (i == n - 1) rp[n] = v + cnt[i];
    }
}

__global__ void k_scatter(const int* __restrict__ er, const int* __restrict__ ec,
                          const float* __restrict__ ev, int* __restrict__ ofs,
                          int* __restrict__ cs, float* __restrict__ vs, int E) {
    for (int e = blockIdx.x * blockDim.x + threadIdx.x; e < E; e += gridDim.x * blockDim.x) {
        int r = er[e];
        int p = atomicAdd(&ofs[r], 1);
        cs[p] = ec[e];
        vs[p] = ev[e];
    }
}

// ---------------- weight split: W[K][M] fp32 -> Wt_hi/Wt_lo[M][K] bf16 ----------------
__global__ void k_split_w(const float* __restrict__ W, unsigned short* __restrict__ hi,
                          unsigned short* __restrict__ lo, int K, int M) {
    int i = blockIdx.x * 256 + threadIdx.x;
    if (i >= K * M) return;
    int k = i / M, m = i - k * M;
    float x = W[i];
    unsigned short h = f2bf_rne(x);
    unsigned short l = f2bf_rne(x - bf2f(h));
    hi[(size_t)m * K + k] = h;
    lo[(size_t)m * K + k] = l;
}

// ---------------- bf16x3-split MFMA GEMM ----------------
// C[N,M] = A[N,K] @ B[K,M], A fp32, B pre-split to Bt_hi/Bt_lo[M][K] bf16.
// Block: 512 thr = 8 waves (2 m-groups x 4 n-groups); wave tile 64 x (16*NF).
// BM=128, BN=64*NF (covers full M in one block). No LDS, no barriers.
template <int K, int NF>
__global__ __launch_bounds__(512, 2)
void k_gemm_mfma(const float* __restrict__ A, const unsigned short* __restrict__ Bhi,
                 const unsigned short* __restrict__ Blo, float* __restrict__ C,
                 const int N, const int M) {
    const int tid = threadIdx.x;
    const int lane = tid & 63;
    const int wid = tid >> 6;
    const int wm = wid >> 2;        // 0..1
    const int wn = wid & 3;         // 0..3
    const int lm = lane & 15;       // frag row (A) / col (B, D)
    const int lk = lane >> 4;       // k-group 0..3

    const int row0 = blockIdx.x * 128 + wm * 64;
    const int col0 = wn * (16 * NF);

    f32x4 acc[4][NF];
    #pragma unroll
    for (int i = 0; i < 4; ++i)
        #pragma unroll
        for (int j = 0; j < NF; ++j) acc[i][j] = (f32x4){0.f, 0.f, 0.f, 0.f};

    #pragma unroll 2
    for (int kk = 0; kk < K; kk += 32) {
        // B fragments (hi+lo), straight from global (L2-resident)
        short8 bh[NF], bl[NF];
        #pragma unroll
        for (int nf = 0; nf < NF; ++nf) {
            const size_t off = (size_t)(col0 + nf * 16 + lm) * K + kk + lk * 8;
            bh[nf] = *(const short8*)&Bhi[off];
            bl[nf] = *(const short8*)&Blo[off];
        }
        #pragma unroll
        for (int mf = 0; mf < 4; ++mf) {
            int row = row0 + mf * 16 + lm;
            int rowc = row < N ? row : N - 1;   // clamp: garbage only pollutes unstored D rows
            const float* ap = A + (size_t)rowc * K + kk + lk * 8;
            float4 a01 = *(const float4*)ap;
            float4 a23 = *(const float4*)(ap + 4);
            float v[8] = {a01.x, a01.y, a01.z, a01.w, a23.x, a23.y, a23.z, a23.w};
            short8 ah, al;
            #pragma unroll
            for (int j = 0; j < 8; ++j) {
                unsigned short h = f2bf_rne(v[j]);
                ah[j] = (short)h;
                al[j] = (short)f2bf_rne(v[j] - bf2f(h));
            }
            #pragma unroll
            for (int nf = 0; nf < NF; ++nf) {
                acc[mf][nf] = __builtin_amdgcn_mfma_f32_16x16x32_bf16(ah, bh[nf], acc[mf][nf], 0, 0, 0);
                acc[mf][nf] = __builtin_amdgcn_mfma_f32_16x16x32_bf16(ah, bl[nf], acc[mf][nf], 0, 0, 0);
                acc[mf][nf] = __builtin_amdgcn_mfma_f32_16x16x32_bf16(al, bh[nf], acc[mf][nf], 0, 0, 0);
            }
        }
    }

    // D layout: col = lane&15, row = (lane>>4)*4 + reg
    #pragma unroll
    for (int mf = 0; mf < 4; ++mf) {
        #pragma unroll
        for (int r = 0; r < 4; ++r) {
            const int row = row0 + mf * 16 + lk * 4 + r;
            if (row < N) {
                #pragma unroll
                for (int nf = 0; nf < NF; ++nf)
                    C[(size_t)row * M + col0 + nf * 16 + lm] = acc[mf][nf][r];
            }
        }
    }
}

// ---------------- SpMM (CSR) + bias + relu ----------------
template <int F>
__global__ void k_spmm_bias_relu(const int* __restrict__ rp, const int* __restrict__ cs,
                                 const float* __restrict__ vs, const float* __restrict__ in,
                                 const float* __restrict__ bias, float* __restrict__ out,
                                 int N) {
    __shared__ int sc[128];
    __shared__ float sv[128];
    int r = blockIdx.x;
    int e0 = rp[r], e1 = rp[r + 1];
    float acc = 0.f;
    for (int base = e0; base < e1; base += 128) {
        int m = min(128, e1 - base);
        if ((int)threadIdx.x < m) {
            sc[threadIdx.x] = cs[base + threadIdx.x];
            sv[threadIdx.x] = vs[base + threadIdx.x];
        }
        __syncthreads();
        int j = 0;
        for (; j + 4 <= m; j += 4) {
            float x0 = in[(size_t)sc[j + 0] * F + threadIdx.x];
            float x1 = in[(size_t)sc[j + 1] * F + threadIdx.x];
            float x2 = in[(size_t)sc[j + 2] * F + threadIdx.x];
            float x3 = in[(size_t)sc[j + 3] * F + threadIdx.x];
            acc = fmaf(sv[j + 0], x0, acc);
            acc = fmaf(sv[j + 1], x1, acc);
            acc = fmaf(sv[j + 2], x2, acc);
            acc = fmaf(sv[j + 3], x3, acc);
        }
        for (; j < m; ++j)
            acc = fmaf(sv[j], in[(size_t)sc[j] * F + threadIdx.x], acc);
        __syncthreads();
    }
    out[(size_t)r * F + threadIdx.x] = fmaxf(acc + bias[threadIdx.x], 0.f);
}

// ---------------- final dense ----------------
__global__ void k_dense(const float* __restrict__ H, const float* __restrict__ Wd,
                        const float* __restrict__ bd, float* __restrict__ out, int N) {
    __shared__ float Ws[H4 * NCLASS];
    for (int i = threadIdx.x; i < H4 * NCLASS; i += blockDim.x) Ws[i] = Wd[i];
    __syncthreads();
    int gid = blockIdx.x * blockDim.x + threadIdx.x;
    if (gid >= N * NCLASS) return;
    int n = gid >> 4, c = gid & 15;
    const float* h = H + (size_t)n * H4;
    float acc = bd[c];
    #pragma unroll 8
    for (int k = 0; k < H4; ++k) acc = fmaf(h[k], Ws[k * NCLASS + c], acc);
    out[gid] = acc;
}

extern "C" void kernel_launch(void* const* d_in, const int* in_sizes, int n_in,
                              void* d_out, int out_size, void* d_ws, size_t ws_size,
                              hipStream_t stream) {
    const float* x  = (const float*)d_in[0];
    const int*   er = (const int*)d_in[1];
    const int*   ec = (const int*)d_in[2];
    const float* ev = (const float*)d_in[3];
    const float* W1 = (const float*)d_in[4];
    const float* b1 = (const float*)d_in[5];
    const float* W2 = (const float*)d_in[6];
    const float* b2 = (const float*)d_in[7];
    const float* W3 = (const float*)d_in[8];
    const float* b3 = (const float*)d_in[9];
    const float* Wd = (const float*)d_in[10];
    const float* bd = (const float*)d_in[11];
    float* out = (float*)d_out;

    int N = in_sizes[0] / NFEAT;
    int E = in_sizes[1];

    char* w = (char*)d_ws;
    float* tmpA = (float*)w; w += (size_t)N * 256 * 4;
    float* tmpB = (float*)w; w += (size_t)N * 256 * 4;
    int* cnt  = (int*)w; w += (size_t)N * 4;
    int* rp   = (int*)w; w += (size_t)(N + 1) * 4 + 12;
    int* ofs  = (int*)w; w += (size_t)N * 4;
    int* cs   = (int*)w; w += (size_t)E * 4;
    float* vs = (float*)w; w += (size_t)E * 4;
    int* bsum = (int*)w; w += 4096;
    unsigned short* W1h = (unsigned short*)w; w += (size_t)NFEAT * H2 * 2;
    unsigned short* W1l = (unsigned short*)w; w += (size_t)NFEAT * H2 * 2;
    unsigned short* W2h = (unsigned short*)w; w += (size_t)H2 * H3 * 2;
    unsigned short* W2l = (unsigned short*)w; w += (size_t)H2 * H3 * 2;
    unsigned short* W3h = (unsigned short*)w; w += (size_t)H3 * H4 * 2;
    unsigned short* W3l = (unsigned short*)w; w += (size_t)H3 * H4 * 2;

    int nb = (N + 255) / 256;

    hipMemsetAsync(cnt, 0, (size_t)N * 4, stream);
    k_hist<<<1024, 256, 0, stream>>>(er, cnt, E);
    k_scan1<<<nb, 256, 0, stream>>>(cnt, rp, bsum, N);
    k_scan2<<<1, 512, 0, stream>>>(bsum, nb);
    k_scan3<<<nb, 256, 0, stream>>>(rp, ofs, bsum, cnt, N);
    k_scatter<<<1024, 256, 0, stream>>>(er, ec, ev, ofs, cs, vs, E);

    k_split_w<<<(NFEAT * H2 + 255) / 256, 256, 0, stream>>>(W1, W1h, W1l, NFEAT, H2);
    k_split_w<<<(H2 * H3 + 255) / 256, 256, 0, stream>>>(W2, W2h, W2l, H2, H3);
    k_split_w<<<(H3 * H4 + 255) / 256, 256, 0, stream>>>(W3, W3h, W3l, H3, H4);

    int ngrid = (N + 127) / 128;
    k_gemm_mfma<NFEAT, 4><<<ngrid, 512, 0, stream>>>(x, W1h, W1l, tmpA, N, H2);
    k_spmm_bias_relu<256><<<N, 256, 0, stream>>>(rp, cs, vs, tmpA, b1, tmpB, N);

    k_gemm_mfma<H2, 4><<<ngrid, 512, 0, stream>>>(tmpB, W2h, W2l, tmpA, N, H3);
    k_spmm_bias_relu<256><<<N, 256, 0, stream>>>(rp, cs, vs, tmpA, b2, tmpB, N);

    k_gemm_mfma<H3, 2><<<ngrid, 512, 0, stream>>>(tmpB, W3h, W3l, tmpA, N, H4);
    k_spmm_bias_relu<128><<<N, 128, 0, stream>>>(rp, cs, vs, tmpA, b3, tmpB, N);

    k_dense<<<(N * NCLASS + 255) / 256, 256, 0, stream>>>(tmpB, Wd, bd, out, N);
}

// Round 3
// 1172.560 us; speedup vs baseline: 1.2592x; 1.1414x over previous
//
#include <hip/hip_runtime.h>
#include <hip/hip_bf16.h>
#include <cstdint>
#include <cstddef>

#define NFEAT 512
#define H2 256
#define H3 256
#define H4 128
#define NCLASS 16

typedef __attribute__((ext_vector_type(8))) short short8;
typedef __attribute__((ext_vector_type(4))) float f32x4;
typedef __attribute__((ext_vector_type(4))) unsigned short ushort4v;

#define AS1 __attribute__((address_space(1)))
#define AS3 __attribute__((address_space(3)))

__device__ inline unsigned short f2bf_rne(float x) {
    unsigned int u = __builtin_bit_cast(unsigned int, x);
    unsigned int r = (u + 0x7FFFu + ((u >> 16) & 1u)) >> 16;
    return (unsigned short)r;
}
__device__ inline float bf2f(unsigned short h) {
    return __builtin_bit_cast(float, (unsigned int)h << 16);
}

// ---------------- CSR build ----------------
__global__ void k_hist(const int* __restrict__ er, int* __restrict__ cnt, int E) {
    for (int e = blockIdx.x * blockDim.x + threadIdx.x; e < E; e += gridDim.x * blockDim.x)
        atomicAdd(&cnt[er[e]], 1);
}

__global__ void k_scan1(const int* __restrict__ cnt, int* __restrict__ ex,
                        int* __restrict__ bsum, int n) {
    __shared__ int s[256];
    int i = blockIdx.x * 256 + threadIdx.x;
    int v = (i < n) ? cnt[i] : 0;
    s[threadIdx.x] = v;
    __syncthreads();
    #pragma unroll
    for (int off = 1; off < 256; off <<= 1) {
        int t = (threadIdx.x >= (unsigned)off) ? s[threadIdx.x - off] : 0;
        __syncthreads();
        s[threadIdx.x] += t;
        __syncthreads();
    }
    if (i < n) ex[i] = s[threadIdx.x] - v;
    if (threadIdx.x == 255) bsum[blockIdx.x] = s[255];
}

__global__ void k_scan2(int* __restrict__ bsum, int nb) {
    __shared__ int s[512];
    int v = ((int)threadIdx.x < nb) ? bsum[threadIdx.x] : 0;
    s[threadIdx.x] = v;
    __syncthreads();
    #pragma unroll
    for (int off = 1; off < 512; off <<= 1) {
        int t = (threadIdx.x >= (unsigned)off) ? s[threadIdx.x - off] : 0;
        __syncthreads();
        s[threadIdx.x] += t;
        __syncthreads();
    }
    if ((int)threadIdx.x < nb) bsum[threadIdx.x] = s[threadIdx.x] - v;
}

__global__ void k_scan3(int* __restrict__ rp, int* __restrict__ ofs,
                        const int* __restrict__ bsum, const int* __restrict__ cnt,
                        int n) {
    int i = blockIdx.x * 256 + threadIdx.x;
    if (i < n) {
        int v = rp[i] + bsum[blockIdx.x];
        rp[i] = v;
        ofs[i] = v;
        if (i == n - 1) rp[n] = v + cnt[i];
    }
}

__global__ void k_scatter(const int* __restrict__ er, const int* __restrict__ ec,
                          const float* __restrict__ ev, int* __restrict__ ofs,
                          int* __restrict__ cs, float* __restrict__ vs, int E) {
    for (int e = blockIdx.x * blockDim.x + threadIdx.x; e < E; e += gridDim.x * blockDim.x) {
        int r = er[e];
        int p = atomicAdd(&ofs[r], 1);
        cs[p] = ec[e];
        vs[p] = ev[e];
    }
}

// ---------------- weight split: W[K][M] fp32 -> [M][K] bf16 hi/lo ----------------
__global__ void k_split_w(const float* __restrict__ W, unsigned short* __restrict__ hi,
                          unsigned short* __restrict__ lo, int K, int M) {
    int i = blockIdx.x * 256 + threadIdx.x;
    if (i >= K * M) return;
    int k = i / M, m = i - k * M;
    float x = W[i];
    unsigned short h = f2bf_rne(x);
    unsigned short l = f2bf_rne(x - bf2f(h));
    hi[(size_t)m * K + k] = h;
    lo[(size_t)m * K + k] = l;
}

// ---------------- x split: fp32 [N][512] -> bf16 hi/lo [N][512] ----------------
__global__ void k_split_x(const float* __restrict__ x, unsigned short* __restrict__ xh,
                          unsigned short* __restrict__ xl, long n4) {
    long i = (long)blockIdx.x * blockDim.x + threadIdx.x;
    if (i >= n4) return;
    float4 v = *(const float4*)&x[i * 4];
    float a[4] = {v.x, v.y, v.z, v.w};
    ushort4v h, l;
    #pragma unroll
    for (int j = 0; j < 4; ++j) {
        unsigned short hh = f2bf_rne(a[j]);
        h[j] = hh;
        l[j] = f2bf_rne(a[j] - bf2f(hh));
    }
    *(ushort4v*)&xh[i * 4] = h;
    *(ushort4v*)&xl[i * 4] = l;
}

// ---------------- bf16x3-split MFMA GEMM, LDS-staged A (m97 structure) ----------------
// C[N,M] = A @ B, A split [N][K] bf16 h/l, B split [M][K] bf16 h/l.
// 256 thr = 4 waves (2wm x 2wn), block tile 128x128, BK=32, dbuf LDS via global_load_lds.
template <int K>
__global__ __launch_bounds__(256, 4)
void k_gemm_split(const unsigned short* __restrict__ Ah, const unsigned short* __restrict__ Al,
                  const unsigned short* __restrict__ Bh, const unsigned short* __restrict__ Bl,
                  float* __restrict__ C, const int N, const int M) {
    constexpr int NT = K / 32;
    __shared__ unsigned short sAh[2][128 * 32];
    __shared__ unsigned short sAl[2][128 * 32];
    const int tid = threadIdx.x;
    const int lane = tid & 63;
    const int w = tid >> 6;
    const int wm = w >> 1, wn = w & 1;
    const int lm = lane & 15, lk = lane >> 4;
    const int row0 = blockIdx.y * 128;
    const int col0 = blockIdx.x * 128 + wn * 64;

    // staging: wave w owns rows [w*32, w*32+32). lane l -> row w*32+(l>>2) (+16 for seg2),
    // global 16B kseg pre-swizzled so linear LDS dest equals swizzled layout.
    const int kseg = (lane & 3) ^ ((lane >> 2) & 3);
    const int grow0 = min(row0 + w * 32 + (lane >> 2), N - 1);
    const int grow1 = min(row0 + w * 32 + 16 + (lane >> 2), N - 1);
    const size_t ga0 = (size_t)grow0 * K + kseg * 8;
    const size_t ga1 = (size_t)grow1 * K + kseg * 8;

    // fragment ds_read offset (ushort units); row&3 == lm&3 so swizzle const across mf
    const int aoff = (wm * 64 + lm) * 32 + ((lk ^ (lm & 3)) * 8);

    const unsigned short* bph = Bh + (size_t)(col0 + lm) * K + lk * 8;
    const unsigned short* bpl = Bl + (size_t)(col0 + lm) * K + lk * 8;

    f32x4 acc[4][4];
    #pragma unroll
    for (int i = 0; i < 4; ++i)
        #pragma unroll
        for (int j = 0; j < 4; ++j) acc[i][j] = (f32x4){0.f, 0.f, 0.f, 0.f};

    auto stage = [&](int b, int kk) {
        __builtin_amdgcn_global_load_lds((const AS1 void*)(Ah + ga0 + kk),
                                         (AS3 void*)&sAh[b][(w * 32) * 32], 16, 0, 0);
        __builtin_amdgcn_global_load_lds((const AS1 void*)(Ah + ga1 + kk),
                                         (AS3 void*)&sAh[b][(w * 32 + 16) * 32], 16, 0, 0);
        __builtin_amdgcn_global_load_lds((const AS1 void*)(Al + ga0 + kk),
                                         (AS3 void*)&sAl[b][(w * 32) * 32], 16, 0, 0);
        __builtin_amdgcn_global_load_lds((const AS1 void*)(Al + ga1 + kk),
                                         (AS3 void*)&sAl[b][(w * 32 + 16) * 32], 16, 0, 0);
    };

    stage(0, 0);
    __syncthreads();

    #pragma unroll 2
    for (int t = 0; t < NT; ++t) {
        if (t + 1 < NT) stage((t + 1) & 1, (t + 1) * 32);
        const int b = t & 1;
        const int kk = t * 32;
        short8 bhf[4], blf[4];
        #pragma unroll
        for (int nf = 0; nf < 4; ++nf) {
            const size_t o = (size_t)nf * 16 * K + kk;
            bhf[nf] = *(const short8*)(bph + o);
            blf[nf] = *(const short8*)(bpl + o);
        }
        #pragma unroll
        for (int mf = 0; mf < 4; ++mf) {
            short8 ah = *(const short8*)&sAh[b][aoff + mf * 512];
            short8 al = *(const short8*)&sAl[b][aoff + mf * 512];
            #pragma unroll
            for (int nf = 0; nf < 4; ++nf) {
                acc[mf][nf] = __builtin_amdgcn_mfma_f32_16x16x32_bf16(ah, bhf[nf], acc[mf][nf], 0, 0, 0);
                acc[mf][nf] = __builtin_amdgcn_mfma_f32_16x16x32_bf16(ah, blf[nf], acc[mf][nf], 0, 0, 0);
                acc[mf][nf] = __builtin_amdgcn_mfma_f32_16x16x32_bf16(al, bhf[nf], acc[mf][nf], 0, 0, 0);
            }
        }
        __syncthreads();
    }

    // D layout: col = lane&15, row = (lane>>4)*4 + r
    #pragma unroll
    for (int mf = 0; mf < 4; ++mf) {
        #pragma unroll
        for (int r = 0; r < 4; ++r) {
            const int row = row0 + wm * 64 + mf * 16 + lk * 4 + r;
            if (row < N) {
                #pragma unroll
                for (int nf = 0; nf < 4; ++nf)
                    C[(size_t)row * M + col0 + nf * 16 + lm] = acc[mf][nf][r];
            }
        }
    }
}

// ---------------- SpMM, wave-per-row, float4 gather, fused bias+relu+split ----------------
__global__ __launch_bounds__(256)
void k_spmm256(const int* __restrict__ rp, const int* __restrict__ cs, const float* __restrict__ vs,
               const float* __restrict__ in, const float* __restrict__ bias,
               unsigned short* __restrict__ oh, unsigned short* __restrict__ ol, int N) {
    const int lane = threadIdx.x & 63;
    const int r = blockIdx.x * 4 + (threadIdx.x >> 6);
    if (r >= N) return;
    const int e0 = rp[r], e1 = rp[r + 1];
    f32x4 acc = {0.f, 0.f, 0.f, 0.f};
    const float* base = in + (size_t)lane * 4;
    int e = e0;
    for (; e + 4 <= e1; e += 4) {
        int c0 = cs[e + 0], c1 = cs[e + 1], c2 = cs[e + 2], c3 = cs[e + 3];
        float v0 = vs[e + 0], v1 = vs[e + 1], v2 = vs[e + 2], v3 = vs[e + 3];
        f32x4 x0 = *(const f32x4*)(base + (size_t)c0 * 256);
        f32x4 x1 = *(const f32x4*)(base + (size_t)c1 * 256);
        f32x4 x2 = *(const f32x4*)(base + (size_t)c2 * 256);
        f32x4 x3 = *(const f32x4*)(base + (size_t)c3 * 256);
        acc += x0 * v0;
        acc += x1 * v1;
        acc += x2 * v2;
        acc += x3 * v3;
    }
    for (; e < e1; ++e) {
        f32x4 x = *(const f32x4*)(base + (size_t)cs[e] * 256);
        acc += x * vs[e];
    }
    f32x4 bv = *(const f32x4*)&bias[lane * 4];
    ushort4v h, l;
    #pragma unroll
    for (int j = 0; j < 4; ++j) {
        float o = fmaxf(acc[j] + bv[j], 0.f);
        unsigned short hh = f2bf_rne(o);
        h[j] = hh;
        l[j] = f2bf_rne(o - bf2f(hh));
    }
    *(ushort4v*)&oh[(size_t)r * 256 + lane * 4] = h;
    *(ushort4v*)&ol[(size_t)r * 256 + lane * 4] = l;
}

__global__ __launch_bounds__(256)
void k_spmm128(const int* __restrict__ rp, const int* __restrict__ cs, const float* __restrict__ vs,
               const float* __restrict__ in, const float* __restrict__ bias,
               float* __restrict__ out, int N) {
    const int lane = threadIdx.x & 63;
    const int r = blockIdx.x * 4 + (threadIdx.x >> 6);
    if (r >= N) return;
    const int e0 = rp[r], e1 = rp[r + 1];
    float a0 = 0.f, a1 = 0.f;
    const float* base = in + (size_t)lane * 2;
    int e = e0;
    for (; e + 4 <= e1; e += 4) {
        int c0 = cs[e + 0], c1 = cs[e + 1], c2 = cs[e + 2], c3 = cs[e + 3];
        float v0 = vs[e + 0], v1 = vs[e + 1], v2 = vs[e + 2], v3 = vs[e + 3];
        float2 x0 = *(const float2*)(base + (size_t)c0 * 128);
        float2 x1 = *(const float2*)(base + (size_t)c1 * 128);
        float2 x2 = *(const float2*)(base + (size_t)c2 * 128);
        float2 x3 = *(const float2*)(base + (size_t)c3 * 128);
        a0 = fmaf(v0, x0.x, a0); a1 = fmaf(v0, x0.y, a1);
        a0 = fmaf(v1, x1.x, a0); a1 = fmaf(v1, x1.y, a1);
        a0 = fmaf(v2, x2.x, a0); a1 = fmaf(v2, x2.y, a1);
        a0 = fmaf(v3, x3.x, a0); a1 = fmaf(v3, x3.y, a1);
    }
    for (; e < e1; ++e) {
        float2 x = *(const float2*)(base + (size_t)cs[e] * 128);
        a0 = fmaf(vs[e], x.x, a0);
        a1 = fmaf(vs[e], x.y, a1);
    }
    float2 o;
    o.x = fmaxf(a0 + bias[lane * 2 + 0], 0.f);
    o.y = fmaxf(a1 + bias[lane * 2 + 1], 0.f);
    *(float2*)&out[(size_t)r * 128 + lane * 2] = o;
}

// ---------------- final dense ----------------
__global__ void k_dense(const float* __restrict__ H, const float* __restrict__ Wd,
                        const float* __restrict__ bd, float* __restrict__ out, int N) {
    __shared__ float Ws[H4 * NCLASS];
    for (int i = threadIdx.x; i < H4 * NCLASS; i += blockDim.x) Ws[i] = Wd[i];
    __syncthreads();
    int gid = blockIdx.x * blockDim.x + threadIdx.x;
    if (gid >= N * NCLASS) return;
    int n = gid >> 4, c = gid & 15;
    const float* h = H + (size_t)n * H4;
    float acc = bd[c];
    #pragma unroll 8
    for (int k = 0; k < H4; ++k) acc = fmaf(h[k], Ws[k * NCLASS + c], acc);
    out[gid] = acc;
}

extern "C" void kernel_launch(void* const* d_in, const int* in_sizes, int n_in,
                              void* d_out, int out_size, void* d_ws, size_t ws_size,
                              hipStream_t stream) {
    const float* x  = (const float*)d_in[0];
    const int*   er = (const int*)d_in[1];
    const int*   ec = (const int*)d_in[2];
    const float* ev = (const float*)d_in[3];
    const float* W1 = (const float*)d_in[4];
    const float* b1 = (const float*)d_in[5];
    const float* W2 = (const float*)d_in[6];
    const float* b2 = (const float*)d_in[7];
    const float* W3 = (const float*)d_in[8];
    const float* b3 = (const float*)d_in[9];
    const float* Wd = (const float*)d_in[10];
    const float* bd = (const float*)d_in[11];
    float* out = (float*)d_out;

    const int N = in_sizes[0] / NFEAT;
    const int E = in_sizes[1];

    char* w = (char*)d_ws;
    auto alloc = [&](size_t bytes) { char* p = w; w += (bytes + 255) & ~(size_t)255; return p; };
    float* C  = (float*)alloc((size_t)N * 256 * 4);
    unsigned short* xh = (unsigned short*)alloc((size_t)N * 512 * 2);
    unsigned short* xl = (unsigned short*)alloc((size_t)N * 512 * 2);
    int* cnt  = (int*)alloc((size_t)N * 4);
    int* rp   = (int*)alloc((size_t)(N + 1) * 4);
    int* ofs  = (int*)alloc((size_t)N * 4);
    int* cs   = (int*)alloc((size_t)E * 4);
    float* vs = (float*)alloc((size_t)E * 4);
    int* bsum = (int*)alloc(4096);
    unsigned short* W1h = (unsigned short*)alloc((size_t)NFEAT * H2 * 2);
    unsigned short* W1l = (unsigned short*)alloc((size_t)NFEAT * H2 * 2);
    unsigned short* W2h = (unsigned short*)alloc((size_t)H2 * H3 * 2);
    unsigned short* W2l = (unsigned short*)alloc((size_t)H2 * H3 * 2);
    unsigned short* W3h = (unsigned short*)alloc((size_t)H3 * H4 * 2);
    unsigned short* W3l = (unsigned short*)alloc((size_t)H3 * H4 * 2);

    unsigned short* hh = xh;               // reuse as [N][256] after GEMM1 consumed x-split
    unsigned short* hl = xl;
    float* h3 = C + (size_t)N * 128;       // second half of C

    const int nb = (N + 255) / 256;

    hipMemsetAsync(cnt, 0, (size_t)N * 4, stream);
    k_hist<<<1024, 256, 0, stream>>>(er, cnt, E);
    k_scan1<<<nb, 256, 0, stream>>>(cnt, rp, bsum, N);
    k_scan2<<<1, 512, 0, stream>>>(bsum, nb);
    k_scan3<<<nb, 256, 0, stream>>>(rp, ofs, bsum, cnt, N);
    k_scatter<<<1024, 256, 0, stream>>>(er, ec, ev, ofs, cs, vs, E);

    k_split_w<<<(NFEAT * H2 + 255) / 256, 256, 0, stream>>>(W1, W1h, W1l, NFEAT, H2);
    k_split_w<<<(H2 * H3 + 255) / 256, 256, 0, stream>>>(W2, W2h, W2l, H2, H3);
    k_split_w<<<(H3 * H4 + 255) / 256, 256, 0, stream>>>(W3, W3h, W3l, H3, H4);

    long n4 = (long)N * NFEAT / 4;
    k_split_x<<<(int)((n4 + 255) / 256), 256, 0, stream>>>(x, xh, xl, n4);

    const int rgrid = (N + 127) / 128;
    const int sgrid = (N + 3) / 4;

    k_gemm_split<NFEAT><<<dim3(2, rgrid), 256, 0, stream>>>(xh, xl, W1h, W1l, C, N, H2);
    k_spmm256<<<sgrid, 256, 0, stream>>>(rp, cs, vs, C, b1, hh, hl, N);

    k_gemm_split<H2><<<dim3(2, rgrid), 256, 0, stream>>>(hh, hl, W2h, W2l, C, N, H3);
    k_spmm256<<<sgrid, 256, 0, stream>>>(rp, cs, vs, C, b2, hh, hl, N);

    k_gemm_split<H3><<<dim3(1, rgrid), 256, 0, stream>>>(hh, hl, W3h, W3l, C, N, H4);
    k_spmm128<<<sgrid, 256, 0, stream>>>(rp, cs, vs, C, b3, h3, N);

    k_dense<<<(N * NCLASS + 255) / 256, 256, 0, stream>>>(h3, Wd, bd, out, N);
}

// Round 4
// 1152.343 us; speedup vs baseline: 1.2813x; 1.0175x over previous
//
#include <hip/hip_runtime.h>
#include <hip/hip_bf16.h>
#include <cstdint>
#include <cstddef>

#define NFEAT 512
#define H2 256
#define H3 256
#define H4 128
#define NCLASS 16

typedef __attribute__((ext_vector_type(8))) short short8;
typedef __attribute__((ext_vector_type(4))) float f32x4;
typedef __attribute__((ext_vector_type(4))) unsigned short ushort4v;

#define AS1 __attribute__((address_space(1)))
#define AS3 __attribute__((address_space(3)))

__device__ inline unsigned short f2bf_rne(float x) {
    unsigned int u = __builtin_bit_cast(unsigned int, x);
    unsigned int r = (u + 0x7FFFu + ((u >> 16) & 1u)) >> 16;
    return (unsigned short)r;
}
__device__ inline float bf2f(unsigned short h) {
    return __builtin_bit_cast(float, (unsigned int)h << 16);
}

// ---------------- CSR build ----------------
__global__ void k_hist(const int* __restrict__ er, int* __restrict__ cnt, int E) {
    for (int e = blockIdx.x * blockDim.x + threadIdx.x; e < E; e += gridDim.x * blockDim.x)
        atomicAdd(&cnt[er[e]], 1);
}

__global__ void k_scan1(const int* __restrict__ cnt, int* __restrict__ ex,
                        int* __restrict__ bsum, int n) {
    __shared__ int s[256];
    int i = blockIdx.x * 256 + threadIdx.x;
    int v = (i < n) ? cnt[i] : 0;
    s[threadIdx.x] = v;
    __syncthreads();
    #pragma unroll
    for (int off = 1; off < 256; off <<= 1) {
        int t = (threadIdx.x >= (unsigned)off) ? s[threadIdx.x - off] : 0;
        __syncthreads();
        s[threadIdx.x] += t;
        __syncthreads();
    }
    if (i < n) ex[i] = s[threadIdx.x] - v;
    if (threadIdx.x == 255) bsum[blockIdx.x] = s[255];
}

__global__ void k_scan2(int* __restrict__ bsum, int nb) {
    __shared__ int s[512];
    int v = ((int)threadIdx.x < nb) ? bsum[threadIdx.x] : 0;
    s[threadIdx.x] = v;
    __syncthreads();
    #pragma unroll
    for (int off = 1; off < 512; off <<= 1) {
        int t = (threadIdx.x >= (unsigned)off) ? s[threadIdx.x - off] : 0;
        __syncthreads();
        s[threadIdx.x] += t;
        __syncthreads();
    }
    if ((int)threadIdx.x < nb) bsum[threadIdx.x] = s[threadIdx.x] - v;
}

__global__ void k_scan3(int* __restrict__ rp, int* __restrict__ ofs,
                        const int* __restrict__ bsum, const int* __restrict__ cnt,
                        int n) {
    int i = blockIdx.x * 256 + threadIdx.x;
    if (i < n) {
        int v = rp[i] + bsum[blockIdx.x];
        rp[i] = v;
        ofs[i] = v;
        if (i == n - 1) rp[n] = v + cnt[i];
    }
}

__global__ void k_scatter(const int* __restrict__ er, const int* __restrict__ ec,
                          const float* __restrict__ ev, int* __restrict__ ofs,
                          int2* __restrict__ ev2, int E) {
    for (int e = blockIdx.x * blockDim.x + threadIdx.x; e < E; e += gridDim.x * blockDim.x) {
        int r = er[e];
        int p = atomicAdd(&ofs[r], 1);
        ev2[p] = make_int2(ec[e], __builtin_bit_cast(int, ev[e]));
    }
}

// ---------------- weight split: W[K][M] fp32 -> [M][K] bf16 hi/lo ----------------
__global__ void k_split_w(const float* __restrict__ W, unsigned short* __restrict__ hi,
                          unsigned short* __restrict__ lo, int K, int M) {
    int i = blockIdx.x * 256 + threadIdx.x;
    if (i >= K * M) return;
    int k = i / M, m = i - k * M;
    float x = W[i];
    unsigned short h = f2bf_rne(x);
    unsigned short l = f2bf_rne(x - bf2f(h));
    hi[(size_t)m * K + k] = h;
    lo[(size_t)m * K + k] = l;
}

// ---------------- x split: fp32 [N][512] -> bf16 hi/lo [N][512] ----------------
__global__ void k_split_x(const float* __restrict__ x, unsigned short* __restrict__ xh,
                          unsigned short* __restrict__ xl, long n4) {
    long i = (long)blockIdx.x * blockDim.x + threadIdx.x;
    if (i >= n4) return;
    float4 v = *(const float4*)&x[i * 4];
    float a[4] = {v.x, v.y, v.z, v.w};
    ushort4v h, l;
    #pragma unroll
    for (int j = 0; j < 4; ++j) {
        unsigned short hh = f2bf_rne(a[j]);
        h[j] = hh;
        l[j] = f2bf_rne(a[j] - bf2f(hh));
    }
    *(ushort4v*)&xh[i * 4] = h;
    *(ushort4v*)&xl[i * 4] = l;
}

// ---------------- bf16x3-split MFMA GEMM, LDS-staged A (m97 structure) ----------------
template <int K>
__global__ __launch_bounds__(256, 4)
void k_gemm_split(const unsigned short* __restrict__ Ah, const unsigned short* __restrict__ Al,
                  const unsigned short* __restrict__ Bh, const unsigned short* __restrict__ Bl,
                  float* __restrict__ C, const int N, const int M) {
    constexpr int NT = K / 32;
    __shared__ unsigned short sAh[2][128 * 32];
    __shared__ unsigned short sAl[2][128 * 32];
    const int tid = threadIdx.x;
    const int lane = tid & 63;
    const int w = tid >> 6;
    const int wm = w >> 1, wn = w & 1;
    const int lm = lane & 15, lk = lane >> 4;
    const int row0 = blockIdx.y * 128;
    const int col0 = blockIdx.x * 128 + wn * 64;

    const int kseg = (lane & 3) ^ ((lane >> 2) & 3);
    const int grow0 = min(row0 + w * 32 + (lane >> 2), N - 1);
    const int grow1 = min(row0 + w * 32 + 16 + (lane >> 2), N - 1);
    const size_t ga0 = (size_t)grow0 * K + kseg * 8;
    const size_t ga1 = (size_t)grow1 * K + kseg * 8;

    const int aoff = (wm * 64 + lm) * 32 + ((lk ^ (lm & 3)) * 8);

    const unsigned short* bph = Bh + (size_t)(col0 + lm) * K + lk * 8;
    const unsigned short* bpl = Bl + (size_t)(col0 + lm) * K + lk * 8;

    f32x4 acc[4][4];
    #pragma unroll
    for (int i = 0; i < 4; ++i)
        #pragma unroll
        for (int j = 0; j < 4; ++j) acc[i][j] = (f32x4){0.f, 0.f, 0.f, 0.f};

    auto stage = [&](int b, int kk) {
        __builtin_amdgcn_global_load_lds((const AS1 void*)(Ah + ga0 + kk),
                                         (AS3 void*)&sAh[b][(w * 32) * 32], 16, 0, 0);
        __builtin_amdgcn_global_load_lds((const AS1 void*)(Ah + ga1 + kk),
                                         (AS3 void*)&sAh[b][(w * 32 + 16) * 32], 16, 0, 0);
        __builtin_amdgcn_global_load_lds((const AS1 void*)(Al + ga0 + kk),
                                         (AS3 void*)&sAl[b][(w * 32) * 32], 16, 0, 0);
        __builtin_amdgcn_global_load_lds((const AS1 void*)(Al + ga1 + kk),
                                         (AS3 void*)&sAl[b][(w * 32 + 16) * 32], 16, 0, 0);
    };

    stage(0, 0);
    __syncthreads();

    #pragma unroll 2
    for (int t = 0; t < NT; ++t) {
        if (t + 1 < NT) stage((t + 1) & 1, (t + 1) * 32);
        const int b = t & 1;
        const int kk = t * 32;
        short8 bhf[4], blf[4];
        #pragma unroll
        for (int nf = 0; nf < 4; ++nf) {
            const size_t o = (size_t)nf * 16 * K + kk;
            bhf[nf] = *(const short8*)(bph + o);
            blf[nf] = *(const short8*)(bpl + o);
        }
        #pragma unroll
        for (int mf = 0; mf < 4; ++mf) {
            short8 ah = *(const short8*)&sAh[b][aoff + mf * 512];
            short8 al = *(const short8*)&sAl[b][aoff + mf * 512];
            #pragma unroll
            for (int nf = 0; nf < 4; ++nf) {
                acc[mf][nf] = __builtin_amdgcn_mfma_f32_16x16x32_bf16(ah, bhf[nf], acc[mf][nf], 0, 0, 0);
                acc[mf][nf] = __builtin_amdgcn_mfma_f32_16x16x32_bf16(ah, blf[nf], acc[mf][nf], 0, 0, 0);
                acc[mf][nf] = __builtin_amdgcn_mfma_f32_16x16x32_bf16(al, bhf[nf], acc[mf][nf], 0, 0, 0);
            }
        }
        __syncthreads();
    }

    #pragma unroll
    for (int mf = 0; mf < 4; ++mf) {
        #pragma unroll
        for (int r = 0; r < 4; ++r) {
            const int row = row0 + wm * 64 + mf * 16 + lk * 4 + r;
            if (row < N) {
                #pragma unroll
                for (int nf = 0; nf < 4; ++nf)
                    C[(size_t)row * M + col0 + nf * 16 + lm] = acc[mf][nf][r];
            }
        }
    }
}

// ---------------- SpMM, wave-per-row, 8-deep gather pipeline, fused bias+relu+split ----------------
__global__ __launch_bounds__(256)
void k_spmm256(const int* __restrict__ rp, const int2* __restrict__ ev2,
               const float* __restrict__ in, const float* __restrict__ bias,
               unsigned short* __restrict__ oh, unsigned short* __restrict__ ol, int N) {
    const int lane = threadIdx.x & 63;
    int r = __builtin_amdgcn_readfirstlane(blockIdx.x * 4 + (threadIdx.x >> 6));
    if (r >= N) return;
    const int e0 = __builtin_amdgcn_readfirstlane(rp[r]);
    const int e1 = __builtin_amdgcn_readfirstlane(rp[r + 1]);
    f32x4 acc = {0.f, 0.f, 0.f, 0.f};
    const float* base = in + (size_t)lane * 4;

    int e = e0;
    const int nfull = (e1 - e0) >> 3;
    if (nfull > 0) {
        int2 cur[8];
        #pragma unroll
        for (int j = 0; j < 8; ++j) cur[j] = ev2[e + j];
        for (int c = 0; c < nfull; ++c) {
            int2 nxt[8];
            const bool more = (c + 1 < nfull);
            if (more) {
                #pragma unroll
                for (int j = 0; j < 8; ++j) nxt[j] = ev2[e + 8 + j];
            }
            #pragma unroll
            for (int j = 0; j < 8; ++j) {
                f32x4 x = *(const f32x4*)(base + (size_t)cur[j].x * 256);
                acc += x * __builtin_bit_cast(float, cur[j].y);
            }
            if (more) {
                #pragma unroll
                for (int j = 0; j < 8; ++j) cur[j] = nxt[j];
            }
            e += 8;
        }
    }
    for (; e < e1; ++e) {
        int2 p = ev2[e];
        f32x4 x = *(const f32x4*)(base + (size_t)p.x * 256);
        acc += x * __builtin_bit_cast(float, p.y);
    }

    f32x4 bv = *(const f32x4*)&bias[lane * 4];
    ushort4v h, l;
    #pragma unroll
    for (int j = 0; j < 4; ++j) {
        float o = fmaxf(acc[j] + bv[j], 0.f);
        unsigned short hh = f2bf_rne(o);
        h[j] = hh;
        l[j] = f2bf_rne(o - bf2f(hh));
    }
    *(ushort4v*)&oh[(size_t)r * 256 + lane * 4] = h;
    *(ushort4v*)&ol[(size_t)r * 256 + lane * 4] = l;
}

__global__ __launch_bounds__(256)
void k_spmm128(const int* __restrict__ rp, const int2* __restrict__ ev2,
               const float* __restrict__ in, const float* __restrict__ bias,
               float* __restrict__ out, int N) {
    const int lane = threadIdx.x & 63;
    int r = __builtin_amdgcn_readfirstlane(blockIdx.x * 4 + (threadIdx.x >> 6));
    if (r >= N) return;
    const int e0 = __builtin_amdgcn_readfirstlane(rp[r]);
    const int e1 = __builtin_amdgcn_readfirstlane(rp[r + 1]);
    float a0 = 0.f, a1 = 0.f;
    const float* base = in + (size_t)lane * 2;

    int e = e0;
    const int nfull = (e1 - e0) >> 3;
    if (nfull > 0) {
        int2 cur[8];
        #pragma unroll
        for (int j = 0; j < 8; ++j) cur[j] = ev2[e + j];
        for (int c = 0; c < nfull; ++c) {
            int2 nxt[8];
            const bool more = (c + 1 < nfull);
            if (more) {
                #pragma unroll
                for (int j = 0; j < 8; ++j) nxt[j] = ev2[e + 8 + j];
            }
            #pragma unroll
            for (int j = 0; j < 8; ++j) {
                float2 x = *(const float2*)(base + (size_t)cur[j].x * 128);
                float v = __builtin_bit_cast(float, cur[j].y);
                a0 = fmaf(v, x.x, a0);
                a1 = fmaf(v, x.y, a1);
            }
            if (more) {
                #pragma unroll
                for (int j = 0; j < 8; ++j) cur[j] = nxt[j];
            }
            e += 8;
        }
    }
    for (; e < e1; ++e) {
        int2 p = ev2[e];
        float2 x = *(const float2*)(base + (size_t)p.x * 128);
        float v = __builtin_bit_cast(float, p.y);
        a0 = fmaf(v, x.x, a0);
        a1 = fmaf(v, x.y, a1);
    }

    float2 o;
    o.x = fmaxf(a0 + bias[lane * 2 + 0], 0.f);
    o.y = fmaxf(a1 + bias[lane * 2 + 1], 0.f);
    *(float2*)&out[(size_t)r * 128 + lane * 2] = o;
}

// ---------------- final dense ----------------
__global__ void k_dense(const float* __restrict__ H, const float* __restrict__ Wd,
                        const float* __restrict__ bd, float* __restrict__ out, int N) {
    __shared__ float Ws[H4 * NCLASS];
    for (int i = threadIdx.x; i < H4 * NCLASS; i += blockDim.x) Ws[i] = Wd[i];
    __syncthreads();
    int gid = blockIdx.x * blockDim.x + threadIdx.x;
    if (gid >= N * NCLASS) return;
    int n = gid >> 4, c = gid & 15;
    const float* h = H + (size_t)n * H4;
    float acc = bd[c];
    #pragma unroll 8
    for (int k = 0; k < H4; ++k) acc = fmaf(h[k], Ws[k * NCLASS + c], acc);
    out[gid] = acc;
}

extern "C" void kernel_launch(void* const* d_in, const int* in_sizes, int n_in,
                              void* d_out, int out_size, void* d_ws, size_t ws_size,
                              hipStream_t stream) {
    const float* x  = (const float*)d_in[0];
    const int*   er = (const int*)d_in[1];
    const int*   ec = (const int*)d_in[2];
    const float* ev = (const float*)d_in[3];
    const float* W1 = (const float*)d_in[4];
    const float* b1 = (const float*)d_in[5];
    const float* W2 = (const float*)d_in[6];
    const float* b2 = (const float*)d_in[7];
    const float* W3 = (const float*)d_in[8];
    const float* b3 = (const float*)d_in[9];
    const float* Wd = (const float*)d_in[10];
    const float* bd = (const float*)d_in[11];
    float* out = (float*)d_out;

    const int N = in_sizes[0] / NFEAT;
    const int E = in_sizes[1];

    char* w = (char*)d_ws;
    auto alloc = [&](size_t bytes) { char* p = w; w += (bytes + 255) & ~(size_t)255; return p; };
    float* C  = (float*)alloc((size_t)N * 256 * 4);
    unsigned short* xh = (unsigned short*)alloc((size_t)N * 512 * 2);
    unsigned short* xl = (unsigned short*)alloc((size_t)N * 512 * 2);
    int* cnt  = (int*)alloc((size_t)N * 4);
    int* rp   = (int*)alloc((size_t)(N + 1) * 4);
    int* ofs  = (int*)alloc((size_t)N * 4);
    int2* ev2 = (int2*)alloc((size_t)E * 8);
    int* bsum = (int*)alloc(4096);
    unsigned short* W1h = (unsigned short*)alloc((size_t)NFEAT * H2 * 2);
    unsigned short* W1l = (unsigned short*)alloc((size_t)NFEAT * H2 * 2);
    unsigned short* W2h = (unsigned short*)alloc((size_t)H2 * H3 * 2);
    unsigned short* W2l = (unsigned short*)alloc((size_t)H2 * H3 * 2);
    unsigned short* W3h = (unsigned short*)alloc((size_t)H3 * H4 * 2);
    unsigned short* W3l = (unsigned short*)alloc((size_t)H3 * H4 * 2);

    unsigned short* hh = xh;               // reuse as [N][256] after GEMM1 consumed x-split
    unsigned short* hl = xl;
    float* h3 = C + (size_t)N * 128;       // second half of C

    const int nb = (N + 255) / 256;

    hipMemsetAsync(cnt, 0, (size_t)N * 4, stream);
    k_hist<<<1024, 256, 0, stream>>>(er, cnt, E);
    k_scan1<<<nb, 256, 0, stream>>>(cnt, rp, bsum, N);
    k_scan2<<<1, 512, 0, stream>>>(bsum, nb);
    k_scan3<<<nb, 256, 0, stream>>>(rp, ofs, bsum, cnt, N);
    k_scatter<<<1024, 256, 0, stream>>>(er, ec, ev, ofs, ev2, E);

    k_split_w<<<(NFEAT * H2 + 255) / 256, 256, 0, stream>>>(W1, W1h, W1l, NFEAT, H2);
    k_split_w<<<(H2 * H3 + 255) / 256, 256, 0, stream>>>(W2, W2h, W2l, H2, H3);
    k_split_w<<<(H3 * H4 + 255) / 256, 256, 0, stream>>>(W3, W3h, W3l, H3, H4);

    long n4 = (long)N * NFEAT / 4;
    k_split_x<<<(int)((n4 + 255) / 256), 256, 0, stream>>>(x, xh, xl, n4);

    const int rgrid = (N + 127) / 128;
    const int sgrid = (N + 3) / 4;

    k_gemm_split<NFEAT><<<dim3(2, rgrid), 256, 0, stream>>>(xh, xl, W1h, W1l, C, N, H2);
    k_spmm256<<<sgrid, 256, 0, stream>>>(rp, ev2, C, b1, hh, hl, N);

    k_gemm_split<H2><<<dim3(2, rgrid), 256, 0, stream>>>(hh, hl, W2h, W2l, C, N, H3);
    k_spmm256<<<sgrid, 256, 0, stream>>>(rp, ev2, C, b2, hh, hl, N);

    k_gemm_split<H3><<<dim3(1, rgrid), 256, 0, stream>>>(hh, hl, W3h, W3l, C, N, H4);
    k_spmm128<<<sgrid, 256, 0, stream>>>(rp, ev2, C, b3, h3, N);

    k_dense<<<(N * NCLASS + 255) / 256, 256, 0, stream>>>(h3, Wd, bd, out, N);
}

// Round 5
// 1098.825 us; speedup vs baseline: 1.3437x; 1.0487x over previous
//
#include <hip/hip_runtime.h>
#include <hip/hip_bf16.h>
#include <cstdint>
#include <cstddef>

#define NFEAT 512
#define H2 256
#define H3 256
#define H4 128
#define NCLASS 16

typedef __attribute__((ext_vector_type(8))) short short8;
typedef __attribute__((ext_vector_type(4))) float f32x4;
typedef __attribute__((ext_vector_type(4))) unsigned short ushort4v;
typedef __attribute__((ext_vector_type(3))) unsigned int uint3v;

#define AS1 __attribute__((address_space(1)))
#define AS3 __attribute__((address_space(3)))

__device__ inline unsigned short f2bf_rne(float x) {
    unsigned int u = __builtin_bit_cast(unsigned int, x);
    unsigned int r = (u + 0x7FFFu + ((u >> 16) & 1u)) >> 16;
    return (unsigned short)r;
}
__device__ inline float bf2f(unsigned short h) {
    return __builtin_bit_cast(float, (unsigned int)h << 16);
}

// ---------------- CSR build ----------------
__global__ void k_hist(const int* __restrict__ er, int* __restrict__ cnt, int E) {
    for (int e = blockIdx.x * blockDim.x + threadIdx.x; e < E; e += gridDim.x * blockDim.x)
        atomicAdd(&cnt[er[e]], 1);
}

__global__ void k_scan1(const int* __restrict__ cnt, int* __restrict__ ex,
                        int* __restrict__ bsum, int n) {
    __shared__ int s[256];
    int i = blockIdx.x * 256 + threadIdx.x;
    int v = (i < n) ? cnt[i] : 0;
    s[threadIdx.x] = v;
    __syncthreads();
    #pragma unroll
    for (int off = 1; off < 256; off <<= 1) {
        int t = (threadIdx.x >= (unsigned)off) ? s[threadIdx.x - off] : 0;
        __syncthreads();
        s[threadIdx.x] += t;
        __syncthreads();
    }
    if (i < n) ex[i] = s[threadIdx.x] - v;
    if (threadIdx.x == 255) bsum[blockIdx.x] = s[255];
}

__global__ void k_scan2(int* __restrict__ bsum, int nb) {
    __shared__ int s[512];
    int v = ((int)threadIdx.x < nb) ? bsum[threadIdx.x] : 0;
    s[threadIdx.x] = v;
    __syncthreads();
    #pragma unroll
    for (int off = 1; off < 512; off <<= 1) {
        int t = (threadIdx.x >= (unsigned)off) ? s[threadIdx.x - off] : 0;
        __syncthreads();
        s[threadIdx.x] += t;
        __syncthreads();
    }
    if ((int)threadIdx.x < nb) bsum[threadIdx.x] = s[threadIdx.x] - v;
}

__global__ void k_scan3(int* __restrict__ rp, int* __restrict__ ofs,
                        const int* __restrict__ bsum, const int* __restrict__ cnt,
                        int n) {
    int i = blockIdx.x * 256 + threadIdx.x;
    if (i < n) {
        int v = rp[i] + bsum[blockIdx.x];
        rp[i] = v;
        ofs[i] = v;
        if (i == n - 1) rp[n] = v + cnt[i];
    }
}

__global__ void k_scatter(const int* __restrict__ er, const int* __restrict__ ec,
                          const float* __restrict__ ev, int* __restrict__ ofs,
                          int2* __restrict__ ev2, int E) {
    for (int e = blockIdx.x * blockDim.x + threadIdx.x; e < E; e += gridDim.x * blockDim.x) {
        int r = er[e];
        int p = atomicAdd(&ofs[r], 1);
        ev2[p] = make_int2(ec[e], __builtin_bit_cast(int, ev[e]));
    }
}

// ---------------- weight split: W[K][M] fp32 -> [M][K] bf16 hi/lo ----------------
__global__ void k_split_w(const float* __restrict__ W, unsigned short* __restrict__ hi,
                          unsigned short* __restrict__ lo, int K, int M) {
    int i = blockIdx.x * 256 + threadIdx.x;
    if (i >= K * M) return;
    int k = i / M, m = i - k * M;
    float x = W[i];
    unsigned short h = f2bf_rne(x);
    unsigned short l = f2bf_rne(x - bf2f(h));
    hi[(size_t)m * K + k] = h;
    lo[(size_t)m * K + k] = l;
}

// ---------------- pack fp32 -> 24-bit (round-half-up on dropped byte) ----------------
// block: 256 threads / 256 groups of 4 floats -> 768 dwords, LDS bounce for coalesced IO
__global__ __launch_bounds__(256)
void k_pack24(const float* __restrict__ in, unsigned int* __restrict__ out, long ngroup) {
    __shared__ unsigned int sp[768];
    long g0 = (long)blockIdx.x * 256;
    long g = g0 + threadIdx.x;
    float4 v = make_float4(0.f, 0.f, 0.f, 0.f);
    if (g < ngroup) v = *(const float4*)&in[g * 4];
    unsigned int t0 = (__builtin_bit_cast(unsigned int, v.x) + 0x80u) >> 8;
    unsigned int t1 = (__builtin_bit_cast(unsigned int, v.y) + 0x80u) >> 8;
    unsigned int t2 = (__builtin_bit_cast(unsigned int, v.z) + 0x80u) >> 8;
    unsigned int t3 = (__builtin_bit_cast(unsigned int, v.w) + 0x80u) >> 8;
    sp[threadIdx.x * 3 + 0] = t0 | (t1 << 24);
    sp[threadIdx.x * 3 + 1] = (t1 >> 8) | (t2 << 16);
    sp[threadIdx.x * 3 + 2] = (t2 >> 16) | (t3 << 8);
    __syncthreads();
    long nvalid = ngroup - g0;
    int total = (int)(nvalid >= 256 ? 768 : nvalid * 3);
    for (int i = threadIdx.x; i < total; i += 256) out[g0 * 3 + i] = sp[i];
}

// ---------------- GEMM1: C[N,256] = x[N,512] @ W1, fp32 A staged in LDS, split in-reg ----------------
__global__ __launch_bounds__(256, 4)
void k_gemm1(const float* __restrict__ X, const unsigned short* __restrict__ Bh,
             const unsigned short* __restrict__ Bl, float* __restrict__ C, const int N) {
    constexpr int K = 512, M = 256, NT = K / 32;
    __shared__ float sX[2][128 * 32];
    const int tid = threadIdx.x;
    const int lane = tid & 63;
    const int w = tid >> 6;
    const int wm = w >> 1, wn = w & 1;
    const int lm = lane & 15, lk = lane >> 4;
    const int row0 = blockIdx.y * 128;
    const int col0 = blockIdx.x * 128 + wn * 64;

    // staging: one instr stages 8 rows (lane>>3) x 16B; kseg pre-swizzled vs row&7
    const int kseg = (lane & 7) ^ ((lane >> 3) & 7);
    size_t ga[4];
    #pragma unroll
    for (int i = 0; i < 4; ++i) {
        int gr = min(row0 + w * 32 + i * 8 + (lane >> 3), N - 1);
        ga[i] = (size_t)gr * K + kseg * 4;
    }

    const unsigned short* bph = Bh + (size_t)(col0 + lm) * K + lk * 8;
    const unsigned short* bpl = Bl + (size_t)(col0 + lm) * K + lk * 8;

    f32x4 acc[4][4];
    #pragma unroll
    for (int i = 0; i < 4; ++i)
        #pragma unroll
        for (int j = 0; j < 4; ++j) acc[i][j] = (f32x4){0.f, 0.f, 0.f, 0.f};

    auto stage = [&](int b, int kk) {
        #pragma unroll
        for (int i = 0; i < 4; ++i)
            __builtin_amdgcn_global_load_lds((const AS1 void*)(X + ga[i] + kk),
                                             (AS3 void*)&sX[b][(w * 32 + i * 8) * 32], 16, 0, 0);
    };

    stage(0, 0);
    __syncthreads();

    const int u0 = ((lk * 2) ^ (lm & 7)) * 4;
    const int u1 = ((lk * 2 + 1) ^ (lm & 7)) * 4;

    for (int t = 0; t < NT; ++t) {
        if (t + 1 < NT) stage((t + 1) & 1, (t + 1) * 32);
        const int b = t & 1;
        const int kk = t * 32;
        short8 bhf[4], blf[4];
        #pragma unroll
        for (int nf = 0; nf < 4; ++nf) {
            const size_t o = (size_t)nf * 16 * K + kk;
            bhf[nf] = *(const short8*)(bph + o);
            blf[nf] = *(const short8*)(bpl + o);
        }
        #pragma unroll
        for (int mf = 0; mf < 4; ++mf) {
            const int rbase = (wm * 64 + mf * 16 + lm) * 32;
            f32x4 p0 = *(const f32x4*)&sX[b][rbase + u0];
            f32x4 p1 = *(const f32x4*)&sX[b][rbase + u1];
            float vv[8] = {p0.x, p0.y, p0.z, p0.w, p1.x, p1.y, p1.z, p1.w};
            short8 ah, al;
            #pragma unroll
            for (int j = 0; j < 8; ++j) {
                unsigned short hh = f2bf_rne(vv[j]);
                ah[j] = (short)hh;
                al[j] = (short)f2bf_rne(vv[j] - bf2f(hh));
            }
            #pragma unroll
            for (int nf = 0; nf < 4; ++nf) {
                acc[mf][nf] = __builtin_amdgcn_mfma_f32_16x16x32_bf16(ah, bhf[nf], acc[mf][nf], 0, 0, 0);
                acc[mf][nf] = __builtin_amdgcn_mfma_f32_16x16x32_bf16(ah, blf[nf], acc[mf][nf], 0, 0, 0);
                acc[mf][nf] = __builtin_amdgcn_mfma_f32_16x16x32_bf16(al, bhf[nf], acc[mf][nf], 0, 0, 0);
            }
        }
        __syncthreads();
    }

    #pragma unroll
    for (int mf = 0; mf < 4; ++mf) {
        #pragma unroll
        for (int r = 0; r < 4; ++r) {
            const int row = row0 + wm * 64 + mf * 16 + lk * 4 + r;
            if (row < N) {
                #pragma unroll
                for (int nf = 0; nf < 4; ++nf)
                    C[(size_t)row * M + col0 + nf * 16 + lm] = acc[mf][nf][r];
            }
        }
    }
}

// ---------------- bf16x3-split MFMA GEMM (A pre-split), m97 structure ----------------
template <int K>
__global__ __launch_bounds__(256, 4)
void k_gemm_split(const unsigned short* __restrict__ Ah, const unsigned short* __restrict__ Al,
                  const unsigned short* __restrict__ Bh, const unsigned short* __restrict__ Bl,
                  float* __restrict__ C, const int N, const int M) {
    constexpr int NT = K / 32;
    __shared__ unsigned short sAh[2][128 * 32];
    __shared__ unsigned short sAl[2][128 * 32];
    const int tid = threadIdx.x;
    const int lane = tid & 63;
    const int w = tid >> 6;
    const int wm = w >> 1, wn = w & 1;
    const int lm = lane & 15, lk = lane >> 4;
    const int row0 = blockIdx.y * 128;
    const int col0 = blockIdx.x * 128 + wn * 64;

    const int kseg = (lane & 3) ^ ((lane >> 2) & 3);
    const int grow0 = min(row0 + w * 32 + (lane >> 2), N - 1);
    const int grow1 = min(row0 + w * 32 + 16 + (lane >> 2), N - 1);
    const size_t ga0 = (size_t)grow0 * K + kseg * 8;
    const size_t ga1 = (size_t)grow1 * K + kseg * 8;

    const int aoff = (wm * 64 + lm) * 32 + ((lk ^ (lm & 3)) * 8);

    const unsigned short* bph = Bh + (size_t)(col0 + lm) * K + lk * 8;
    const unsigned short* bpl = Bl + (size_t)(col0 + lm) * K + lk * 8;

    f32x4 acc[4][4];
    #pragma unroll
    for (int i = 0; i < 4; ++i)
        #pragma unroll
        for (int j = 0; j < 4; ++j) acc[i][j] = (f32x4){0.f, 0.f, 0.f, 0.f};

    auto stage = [&](int b, int kk) {
        __builtin_amdgcn_global_load_lds((const AS1 void*)(Ah + ga0 + kk),
                                         (AS3 void*)&sAh[b][(w * 32) * 32], 16, 0, 0);
        __builtin_amdgcn_global_load_lds((const AS1 void*)(Ah + ga1 + kk),
                                         (AS3 void*)&sAh[b][(w * 32 + 16) * 32], 16, 0, 0);
        __builtin_amdgcn_global_load_lds((const AS1 void*)(Al + ga0 + kk),
                                         (AS3 void*)&sAl[b][(w * 32) * 32], 16, 0, 0);
        __builtin_amdgcn_global_load_lds((const AS1 void*)(Al + ga1 + kk),
                                         (AS3 void*)&sAl[b][(w * 32 + 16) * 32], 16, 0, 0);
    };

    stage(0, 0);
    __syncthreads();

    #pragma unroll 2
    for (int t = 0; t < NT; ++t) {
        if (t + 1 < NT) stage((t + 1) & 1, (t + 1) * 32);
        const int b = t & 1;
        const int kk = t * 32;
        short8 bhf[4], blf[4];
        #pragma unroll
        for (int nf = 0; nf < 4; ++nf) {
            const size_t o = (size_t)nf * 16 * K + kk;
            bhf[nf] = *(const short8*)(bph + o);
            blf[nf] = *(const short8*)(bpl + o);
        }
        #pragma unroll
        for (int mf = 0; mf < 4; ++mf) {
            short8 ah = *(const short8*)&sAh[b][aoff + mf * 512];
            short8 al = *(const short8*)&sAl[b][aoff + mf * 512];
            #pragma unroll
            for (int nf = 0; nf < 4; ++nf) {
                acc[mf][nf] = __builtin_amdgcn_mfma_f32_16x16x32_bf16(ah, bhf[nf], acc[mf][nf], 0, 0, 0);
                acc[mf][nf] = __builtin_amdgcn_mfma_f32_16x16x32_bf16(ah, blf[nf], acc[mf][nf], 0, 0, 0);
                acc[mf][nf] = __builtin_amdgcn_mfma_f32_16x16x32_bf16(al, bhf[nf], acc[mf][nf], 0, 0, 0);
            }
        }
        __syncthreads();
    }

    #pragma unroll
    for (int mf = 0; mf < 4; ++mf) {
        #pragma unroll
        for (int r = 0; r < 4; ++r) {
            const int row = row0 + wm * 64 + mf * 16 + lk * 4 + r;
            if (row < N) {
                #pragma unroll
                for (int nf = 0; nf < 4; ++nf)
                    C[(size_t)row * M + col0 + nf * 16 + lm] = acc[mf][nf][r];
            }
        }
    }
}

// ---------------- SpMM on 24-bit packed input, wave-per-row, fused bias+relu+split ----------------
__global__ __launch_bounds__(256)
void k_spmm256p(const int* __restrict__ rp, const int2* __restrict__ ev2,
                const unsigned int* __restrict__ in24, const float* __restrict__ bias,
                unsigned short* __restrict__ oh, unsigned short* __restrict__ ol, int N) {
    const int lane = threadIdx.x & 63;
    int r = __builtin_amdgcn_readfirstlane(blockIdx.x * 4 + (threadIdx.x >> 6));
    if (r >= N) return;
    const int e0 = __builtin_amdgcn_readfirstlane(rp[r]);
    const int e1 = __builtin_amdgcn_readfirstlane(rp[r + 1]);
    f32x4 acc = {0.f, 0.f, 0.f, 0.f};
    const unsigned int* base = in24 + lane * 3;   // row = 192 dwords (256 feats x 3B)

    #pragma unroll 4
    for (int e = e0; e < e1; ++e) {
        int2 p = ev2[e];
        uint3v d = *(const uint3v*)(base + (size_t)p.x * 192);
        float val = __builtin_bit_cast(float, p.y);
        unsigned int q0 = d.x & 0xFFFFFFu;
        unsigned int q1 = (d.x >> 24) | ((d.y & 0xFFFFu) << 8);
        unsigned int q2 = (d.y >> 16) | ((d.z & 0xFFu) << 16);
        unsigned int q3 = d.z >> 8;
        acc[0] = fmaf(val, __builtin_bit_cast(float, q0 << 8), acc[0]);
        acc[1] = fmaf(val, __builtin_bit_cast(float, q1 << 8), acc[1]);
        acc[2] = fmaf(val, __builtin_bit_cast(float, q2 << 8), acc[2]);
        acc[3] = fmaf(val, __builtin_bit_cast(float, q3 << 8), acc[3]);
    }

    f32x4 bv = *(const f32x4*)&bias[lane * 4];
    ushort4v h, l;
    #pragma unroll
    for (int j = 0; j < 4; ++j) {
        float o = fmaxf(acc[j] + bv[j], 0.f);
        unsigned short hh = f2bf_rne(o);
        h[j] = hh;
        l[j] = f2bf_rne(o - bf2f(hh));
    }
    *(ushort4v*)&oh[(size_t)r * 256 + lane * 4] = h;
    *(ushort4v*)&ol[(size_t)r * 256 + lane * 4] = l;
}

// ---------------- SpMM F=128 (fp32 in) + fused bias/relu + final dense ----------------
__global__ __launch_bounds__(256)
void k_spmm128d(const int* __restrict__ rp, const int2* __restrict__ ev2,
                const float* __restrict__ in, const float* __restrict__ b3,
                const float* __restrict__ Wd, const float* __restrict__ bd,
                float* __restrict__ out, int N) {
    __shared__ float Ws[H4 * NCLASS];   // 8 KB
    __shared__ float hrow[4][H4];       // 2 KB
    {
        int i = threadIdx.x * 8;
        *(f32x4*)&Ws[i] = *(const f32x4*)&Wd[i];
        *(f32x4*)&Ws[i + 4] = *(const f32x4*)&Wd[i + 4];
    }
    __syncthreads();

    const int lane = threadIdx.x & 63;
    const int w = threadIdx.x >> 6;
    int r = __builtin_amdgcn_readfirstlane(blockIdx.x * 4 + w);
    if (r >= N) return;
    const int e0 = __builtin_amdgcn_readfirstlane(rp[r]);
    const int e1 = __builtin_amdgcn_readfirstlane(rp[r + 1]);
    float a0 = 0.f, a1 = 0.f;
    const float* base = in + (size_t)lane * 2;

    #pragma unroll 4
    for (int e = e0; e < e1; ++e) {
        int2 p = ev2[e];
        float2 x = *(const float2*)(base + (size_t)p.x * 128);
        float v = __builtin_bit_cast(float, p.y);
        a0 = fmaf(v, x.x, a0);
        a1 = fmaf(v, x.y, a1);
    }

    float2 hb;
    hb.x = fmaxf(a0 + b3[lane * 2 + 0], 0.f);
    hb.y = fmaxf(a1 + b3[lane * 2 + 1], 0.f);
    *(float2*)&hrow[w][lane * 2] = hb;

    // dense: out[r,c] = sum_k hrow[k] * Ws[k*16+c] + bd[c]
    const int c = lane & 15, q = lane >> 4;
    float s = 0.f;
    #pragma unroll
    for (int k = q * 32; k < q * 32 + 32; ++k)
        s = fmaf(hrow[w][k], Ws[k * NCLASS + c], s);
    s += __shfl_xor(s, 16);
    s += __shfl_xor(s, 32);
    if (lane < 16) out[(size_t)r * NCLASS + lane] = s + bd[lane];
}

extern "C" void kernel_launch(void* const* d_in, const int* in_sizes, int n_in,
                              void* d_out, int out_size, void* d_ws, size_t ws_size,
                              hipStream_t stream) {
    const float* x  = (const float*)d_in[0];
    const int*   er = (const int*)d_in[1];
    const int*   ec = (const int*)d_in[2];
    const float* ev = (const float*)d_in[3];
    const float* W1 = (const float*)d_in[4];
    const float* b1 = (const float*)d_in[5];
    const float* W2 = (const float*)d_in[6];
    const float* b2 = (const float*)d_in[7];
    const float* W3 = (const float*)d_in[8];
    const float* b3 = (const float*)d_in[9];
    const float* Wd = (const float*)d_in[10];
    const float* bd = (const float*)d_in[11];
    float* out = (float*)d_out;

    const int N = in_sizes[0] / NFEAT;
    const int E = in_sizes[1];

    char* w = (char*)d_ws;
    auto alloc = [&](size_t bytes) { char* p = w; w += (bytes + 255) & ~(size_t)255; return p; };
    float* C   = (float*)alloc((size_t)N * 256 * 4);
    unsigned int* C24 = (unsigned int*)alloc((size_t)N * 256 * 3);
    unsigned short* hh = (unsigned short*)alloc((size_t)N * 256 * 2);
    unsigned short* hl = (unsigned short*)alloc((size_t)N * 256 * 2);
    int* cnt  = (int*)alloc((size_t)N * 4);
    int* rp   = (int*)alloc((size_t)(N + 1) * 4);
    int* ofs  = (int*)alloc((size_t)N * 4);
    int2* ev2 = (int2*)alloc((size_t)E * 8);
    int* bsum = (int*)alloc(4096);
    unsigned short* W1h = (unsigned short*)alloc((size_t)NFEAT * H2 * 2);
    unsigned short* W1l = (unsigned short*)alloc((size_t)NFEAT * H2 * 2);
    unsigned short* W2h = (unsigned short*)alloc((size_t)H2 * H3 * 2);
    unsigned short* W2l = (unsigned short*)alloc((size_t)H2 * H3 * 2);
    unsigned short* W3h = (unsigned short*)alloc((size_t)H3 * H4 * 2);
    unsigned short* W3l = (unsigned short*)alloc((size_t)H3 * H4 * 2);

    const int nb = (N + 255) / 256;

    hipMemsetAsync(cnt, 0, (size_t)N * 4, stream);
    k_hist<<<1024, 256, 0, stream>>>(er, cnt, E);
    k_scan1<<<nb, 256, 0, stream>>>(cnt, rp, bsum, N);
    k_scan2<<<1, 512, 0, stream>>>(bsum, nb);
    k_scan3<<<nb, 256, 0, stream>>>(rp, ofs, bsum, cnt, N);
    k_scatter<<<1024, 256, 0, stream>>>(er, ec, ev, ofs, ev2, E);

    k_split_w<<<(NFEAT * H2 + 255) / 256, 256, 0, stream>>>(W1, W1h, W1l, NFEAT, H2);
    k_split_w<<<(H2 * H3 + 255) / 256, 256, 0, stream>>>(W2, W2h, W2l, H2, H3);
    k_split_w<<<(H3 * H4 + 255) / 256, 256, 0, stream>>>(W3, W3h, W3l, H3, H4);

    const int rgrid = (N + 127) / 128;
    const int sgrid = (N + 3) / 4;
    const long ngroup = (long)N * 256 / 4;
    const int pgrid = (int)((ngroup + 255) / 256);

    k_gemm1<<<dim3(2, rgrid), 256, 0, stream>>>(x, W1h, W1l, C, N);
    k_pack24<<<pgrid, 256, 0, stream>>>(C, C24, ngroup);
    k_spmm256p<<<sgrid, 256, 0, stream>>>(rp, ev2, C24, b1, hh, hl, N);

    k_gemm_split<H2><<<dim3(2, rgrid), 256, 0, stream>>>(hh, hl, W2h, W2l, C, N, H3);
    k_pack24<<<pgrid, 256, 0, stream>>>(C, C24, ngroup);
    k_spmm256p<<<sgrid, 256, 0, stream>>>(rp, ev2, C24, b2, hh, hl, N);

    k_gemm_split<H3><<<dim3(1, rgrid), 256, 0, stream>>>(hh, hl, W3h, W3l, C, N, H4);
    k_spmm128d<<<sgrid, 256, 0, stream>>>(rp, ev2, C, b3, Wd, bd, out, N);
}

// Round 6
// 1023.707 us; speedup vs baseline: 1.4423x; 1.0734x over previous
//
#include <hip/hip_runtime.h>
#include <hip/hip_bf16.h>
#include <cstdint>
#include <cstddef>

#define NFEAT 512
#define H2 256
#define H3 256
#define H4 128
#define NCLASS 16

typedef __attribute__((ext_vector_type(8))) short short8;
typedef __attribute__((ext_vector_type(4))) float f32x4;
typedef __attribute__((ext_vector_type(4))) unsigned short ushort4v;
typedef __attribute__((ext_vector_type(3))) unsigned int uint3v;

#define AS1 __attribute__((address_space(1)))
#define AS3 __attribute__((address_space(3)))

__device__ inline unsigned short f2bf_rne(float x) {
    unsigned int u = __builtin_bit_cast(unsigned int, x);
    unsigned int r = (u + 0x7FFFu + ((u >> 16) & 1u)) >> 16;
    return (unsigned short)r;
}
__device__ inline float bf2f(unsigned short h) {
    return __builtin_bit_cast(float, (unsigned int)h << 16);
}

// ---------------- CSR build ----------------
__global__ void k_hist(const int* __restrict__ er, int* __restrict__ cnt, int E) {
    for (int e = blockIdx.x * blockDim.x + threadIdx.x; e < E; e += gridDim.x * blockDim.x)
        atomicAdd(&cnt[er[e]], 1);
}

__global__ void k_scan1(const int* __restrict__ cnt, int* __restrict__ ex,
                        int* __restrict__ bsum, int n) {
    __shared__ int s[256];
    int i = blockIdx.x * 256 + threadIdx.x;
    int v = (i < n) ? cnt[i] : 0;
    s[threadIdx.x] = v;
    __syncthreads();
    #pragma unroll
    for (int off = 1; off < 256; off <<= 1) {
        int t = (threadIdx.x >= (unsigned)off) ? s[threadIdx.x - off] : 0;
        __syncthreads();
        s[threadIdx.x] += t;
        __syncthreads();
    }
    if (i < n) ex[i] = s[threadIdx.x] - v;
    if (threadIdx.x == 255) bsum[blockIdx.x] = s[255];
}

__global__ void k_scan2(int* __restrict__ bsum, int nb) {
    __shared__ int s[512];
    int v = ((int)threadIdx.x < nb) ? bsum[threadIdx.x] : 0;
    s[threadIdx.x] = v;
    __syncthreads();
    #pragma unroll
    for (int off = 1; off < 512; off <<= 1) {
        int t = (threadIdx.x >= (unsigned)off) ? s[threadIdx.x - off] : 0;
        __syncthreads();
        s[threadIdx.x] += t;
        __syncthreads();
    }
    if ((int)threadIdx.x < nb) bsum[threadIdx.x] = s[threadIdx.x] - v;
}

__global__ void k_scan3(int* __restrict__ rp, int* __restrict__ ofs,
                        const int* __restrict__ bsum, const int* __restrict__ cnt,
                        int n) {
    int i = blockIdx.x * 256 + threadIdx.x;
    if (i < n) {
        int v = rp[i] + bsum[blockIdx.x];
        rp[i] = v;
        ofs[i] = v;
        if (i == n - 1) rp[n] = v + cnt[i];
    }
}

__global__ void k_scatter(const int* __restrict__ er, const int* __restrict__ ec,
                          const float* __restrict__ ev, int* __restrict__ ofs,
                          int2* __restrict__ ev2, int E) {
    for (int e = blockIdx.x * blockDim.x + threadIdx.x; e < E; e += gridDim.x * blockDim.x) {
        int r = er[e];
        int p = atomicAdd(&ofs[r], 1);
        ev2[p] = make_int2(ec[e], __builtin_bit_cast(int, ev[e]));
    }
}

// ---------------- weight split: W[K][M] fp32 -> [M][K] bf16 hi/lo ----------------
__global__ void k_split_w(const float* __restrict__ W, unsigned short* __restrict__ hi,
                          unsigned short* __restrict__ lo, int K, int M) {
    int i = blockIdx.x * 256 + threadIdx.x;
    if (i >= K * M) return;
    int k = i / M, m = i - k * M;
    float x = W[i];
    unsigned short h = f2bf_rne(x);
    unsigned short l = f2bf_rne(x - bf2f(h));
    hi[(size_t)m * K + k] = h;
    lo[(size_t)m * K + k] = l;
}

// ---------------- pack fp32 -> 24-bit (round-half-up on dropped byte) ----------------
__global__ __launch_bounds__(256)
void k_pack24(const float* __restrict__ in, unsigned int* __restrict__ out, long ngroup) {
    __shared__ unsigned int sp[768];
    long g0 = (long)blockIdx.x * 256;
    long g = g0 + threadIdx.x;
    float4 v = make_float4(0.f, 0.f, 0.f, 0.f);
    if (g < ngroup) v = *(const float4*)&in[g * 4];
    unsigned int t0 = (__builtin_bit_cast(unsigned int, v.x) + 0x80u) >> 8;
    unsigned int t1 = (__builtin_bit_cast(unsigned int, v.y) + 0x80u) >> 8;
    unsigned int t2 = (__builtin_bit_cast(unsigned int, v.z) + 0x80u) >> 8;
    unsigned int t3 = (__builtin_bit_cast(unsigned int, v.w) + 0x80u) >> 8;
    sp[threadIdx.x * 3 + 0] = t0 | (t1 << 24);
    sp[threadIdx.x * 3 + 1] = (t1 >> 8) | (t2 << 16);
    sp[threadIdx.x * 3 + 2] = (t2 >> 16) | (t3 << 8);
    __syncthreads();
    long nvalid = ngroup - g0;
    int total = (int)(nvalid >= 256 ? 768 : nvalid * 3);
    for (int i = threadIdx.x; i < total; i += 256) out[g0 * 3 + i] = sp[i];
}

// ---------------- GEMM1: C[N,256] = X[N,512] @ W1. fp32 A staged, split in-reg.
// 256 thr = 4 waves, block tile 64 x 256 (full M -> X read once).
__global__ __launch_bounds__(256, 2)
void k_gemm1w(const float* __restrict__ X, const unsigned short* __restrict__ Bh,
              const unsigned short* __restrict__ Bl, float* __restrict__ C, const int N) {
    constexpr int K = 512, M = 256, NT = K / 32;
    __shared__ char smem[16384];            // dbuf A: 2 x 64x32 fp32 = 16 KB; epilogue scratch aliases
    float* sX = (float*)smem;
    const int tid = threadIdx.x;
    const int lane = tid & 63;
    const int w = tid >> 6;                 // wave: col group AND staging row group
    const int lm = lane & 15, lk = lane >> 4;
    const int row0 = blockIdx.x * 64;
    const int col0 = w * 64;

    // staging: wave w stages rows [w*16, w*16+16), 2 loads of 8 rows; global kseg pre-swizzled
    const int kseg = (lane & 7) ^ ((lane >> 3) & 7);
    const int r0 = min(row0 + w * 16 + (lane >> 3), N - 1);
    const int r1 = min(row0 + w * 16 + 8 + (lane >> 3), N - 1);
    const size_t ga0 = (size_t)r0 * K + kseg * 4;
    const size_t ga1 = (size_t)r1 * K + kseg * 4;

    const unsigned short* bph = Bh + (size_t)(col0 + lm) * K + lk * 8;
    const unsigned short* bpl = Bl + (size_t)(col0 + lm) * K + lk * 8;

    f32x4 acc[4][4];
    #pragma unroll
    for (int i = 0; i < 4; ++i)
        #pragma unroll
        for (int j = 0; j < 4; ++j) acc[i][j] = (f32x4){0.f, 0.f, 0.f, 0.f};

    auto stage = [&](int b, int kk) {
        __builtin_amdgcn_global_load_lds((const AS1 void*)(X + ga0 + kk),
                                         (AS3 void*)(sX + b * 2048 + w * 512), 16, 0, 0);
        __builtin_amdgcn_global_load_lds((const AS1 void*)(X + ga1 + kk),
                                         (AS3 void*)(sX + b * 2048 + w * 512 + 256), 16, 0, 0);
    };

    stage(0, 0);
    __syncthreads();

    const int u0 = ((2 * lk) ^ (lm & 7)) * 4;       // float offsets of the 2 swizzled 16B units
    const int u1 = ((2 * lk + 1) ^ (lm & 7)) * 4;

    for (int t = 0; t < NT; ++t) {
        if (t + 1 < NT) stage((t + 1) & 1, (t + 1) * 32);
        const float* sb = sX + (t & 1) * 2048;
        const int kk = t * 32;
        short8 bhf[4], blf[4];
        #pragma unroll
        for (int nf = 0; nf < 4; ++nf) {
            const size_t o = (size_t)nf * 16 * K + kk;
            bhf[nf] = *(const short8*)(bph + o);
            blf[nf] = *(const short8*)(bpl + o);
        }
        #pragma unroll
        for (int mf = 0; mf < 4; ++mf) {
            const float* ab = sb + (mf * 16 + lm) * 32;
            f32x4 p0 = *(const f32x4*)(ab + u0);
            f32x4 p1 = *(const f32x4*)(ab + u1);
            float vv[8] = {p0.x, p0.y, p0.z, p0.w, p1.x, p1.y, p1.z, p1.w};
            short8 ah, al;
            #pragma unroll
            for (int j = 0; j < 8; ++j) {
                unsigned int u = __builtin_bit_cast(unsigned int, vv[j]);
                ah[j] = (short)(u >> 16);                                   // truncated hi
                float hi = __builtin_bit_cast(float, u & 0xFFFF0000u);
                al[j] = (short)f2bf_rne(vv[j] - hi);                        // exact remainder -> bf16
            }
            #pragma unroll
            for (int nf = 0; nf < 4; ++nf) {
                acc[mf][nf] = __builtin_amdgcn_mfma_f32_16x16x32_bf16(ah, bhf[nf], acc[mf][nf], 0, 0, 0);
                acc[mf][nf] = __builtin_amdgcn_mfma_f32_16x16x32_bf16(ah, blf[nf], acc[mf][nf], 0, 0, 0);
                acc[mf][nf] = __builtin_amdgcn_mfma_f32_16x16x32_bf16(al, bhf[nf], acc[mf][nf], 0, 0, 0);
            }
        }
        __syncthreads();
    }

    // epilogue: LDS bounce per mf-slice -> float4 coalesced stores (full 128B lines)
    float* sc = (float*)smem;               // 16 rows x 256 cols fp32 = 16 KB
    #pragma unroll
    for (int mf = 0; mf < 4; ++mf) {
        __syncthreads();
        #pragma unroll
        for (int nf = 0; nf < 4; ++nf)
            #pragma unroll
            for (int r = 0; r < 4; ++r) {
                const int rl = lk * 4 + r;
                const int col = col0 + nf * 16 + lm;
                sc[rl * M + (col ^ (lk << 3))] = acc[mf][nf][r];
            }
        __syncthreads();
        #pragma unroll
        for (int i = 0; i < 4; ++i) {
            const int idx = i * 256 + tid;
            const int rl = idx >> 6, u = idx & 63;
            const int grow = row0 + mf * 16 + rl;
            if (grow < N) {
                f32x4 v = *(const f32x4*)&sc[rl * M + ((u * 4) ^ (((rl >> 2) & 3) << 3))];
                *(f32x4*)&C[(size_t)grow * M + u * 4] = v;
            }
        }
    }
}

// ---------------- GEMM (A pre-split bf16 h/l): block tile 64 x (64*NFW), full M ----------------
template <int K, int NFW>
__global__ __launch_bounds__(256, 2)
void k_gemm_bt(const unsigned short* __restrict__ Ah, const unsigned short* __restrict__ Al,
               const unsigned short* __restrict__ Bh, const unsigned short* __restrict__ Bl,
               float* __restrict__ C, const int N) {
    constexpr int M = 64 * NFW;
    constexpr int NT = K / 32;
    constexpr int UPR = 16 * NFW;           // float4 units per row
    __shared__ char smem[16384];
    unsigned short* sAh = (unsigned short*)smem;          // [2][64*32]
    unsigned short* sAl = sAh + 4096;                     // [2][64*32]
    const int tid = threadIdx.x;
    const int lane = tid & 63;
    const int w = tid >> 6;
    const int lm = lane & 15, lk = lane >> 4;
    const int row0 = blockIdx.x * 64;
    const int col0 = w * (16 * NFW);

    const int kseg = (lane & 3) ^ ((lane >> 2) & 3);
    const int gr = min(row0 + w * 16 + (lane >> 2), N - 1);
    const size_t ga = (size_t)gr * K + kseg * 8;

    const int aoff = lm * 32 + ((lk ^ (lm & 3)) * 8);     // + mf*512

    const unsigned short* bph = Bh + (size_t)(col0 + lm) * K + lk * 8;
    const unsigned short* bpl = Bl + (size_t)(col0 + lm) * K + lk * 8;

    f32x4 acc[4][NFW];
    #pragma unroll
    for (int i = 0; i < 4; ++i)
        #pragma unroll
        for (int j = 0; j < NFW; ++j) acc[i][j] = (f32x4){0.f, 0.f, 0.f, 0.f};

    auto stage = [&](int b, int kk) {
        __builtin_amdgcn_global_load_lds((const AS1 void*)(Ah + ga + kk),
                                         (AS3 void*)(sAh + b * 2048 + w * 512), 16, 0, 0);
        __builtin_amdgcn_global_load_lds((const AS1 void*)(Al + ga + kk),
                                         (AS3 void*)(sAl + b * 2048 + w * 512), 16, 0, 0);
    };

    stage(0, 0);
    __syncthreads();

    for (int t = 0; t < NT; ++t) {
        if (t + 1 < NT) stage((t + 1) & 1, (t + 1) * 32);
        const int b = t & 1;
        const int kk = t * 32;
        short8 bhf[NFW], blf[NFW];
        #pragma unroll
        for (int nf = 0; nf < NFW; ++nf) {
            const size_t o = (size_t)nf * 16 * K + kk;
            bhf[nf] = *(const short8*)(bph + o);
            blf[nf] = *(const short8*)(bpl + o);
        }
        #pragma unroll
        for (int mf = 0; mf < 4; ++mf) {
            short8 ah = *(const short8*)&sAh[b * 2048 + aoff + mf * 512];
            short8 al = *(const short8*)&sAl[b * 2048 + aoff + mf * 512];
            #pragma unroll
            for (int nf = 0; nf < NFW; ++nf) {
                acc[mf][nf] = __builtin_amdgcn_mfma_f32_16x16x32_bf16(ah, bhf[nf], acc[mf][nf], 0, 0, 0);
                acc[mf][nf] = __builtin_amdgcn_mfma_f32_16x16x32_bf16(ah, blf[nf], acc[mf][nf], 0, 0, 0);
                acc[mf][nf] = __builtin_amdgcn_mfma_f32_16x16x32_bf16(al, bhf[nf], acc[mf][nf], 0, 0, 0);
            }
        }
        __syncthreads();
    }

    float* sc = (float*)smem;               // 16 x M fp32 (<= 16 KB)
    #pragma unroll
    for (int mf = 0; mf < 4; ++mf) {
        __syncthreads();
        #pragma unroll
        for (int nf = 0; nf < NFW; ++nf)
            #pragma unroll
            for (int r = 0; r < 4; ++r) {
                const int rl = lk * 4 + r;
                const int col = col0 + nf * 16 + lm;
                sc[rl * M + (col ^ (lk << 3))] = acc[mf][nf][r];
            }
        __syncthreads();
        #pragma unroll
        for (int i = 0; i < (16 * UPR) / 256; ++i) {
            const int idx = i * 256 + tid;
            const int rl = idx / UPR, u = idx % UPR;
            const int grow = row0 + mf * 16 + rl;
            if (grow < N) {
                f32x4 v = *(const f32x4*)&sc[rl * M + ((u * 4) ^ (((rl >> 2) & 3) << 3))];
                *(f32x4*)&C[(size_t)grow * M + u * 4] = v;
            }
        }
    }
}

// ---------------- SpMM on 24-bit packed input, wave-per-row, fused bias+relu+split ----------------
__global__ __launch_bounds__(256)
void k_spmm256p(const int* __restrict__ rp, const int2* __restrict__ ev2,
                const unsigned int* __restrict__ in24, const float* __restrict__ bias,
                unsigned short* __restrict__ oh, unsigned short* __restrict__ ol, int N) {
    const int lane = threadIdx.x & 63;
    int r = __builtin_amdgcn_readfirstlane(blockIdx.x * 4 + (threadIdx.x >> 6));
    if (r >= N) return;
    const int e0 = __builtin_amdgcn_readfirstlane(rp[r]);
    const int e1 = __builtin_amdgcn_readfirstlane(rp[r + 1]);
    f32x4 acc = {0.f, 0.f, 0.f, 0.f};
    const unsigned int* base = in24 + lane * 3;

    #pragma unroll 4
    for (int e = e0; e < e1; ++e) {
        int2 p = ev2[e];
        uint3v d = *(const uint3v*)(base + (size_t)p.x * 192);
        float val = __builtin_bit_cast(float, p.y);
        unsigned int q0 = d.x & 0xFFFFFFu;
        unsigned int q1 = (d.x >> 24) | ((d.y & 0xFFFFu) << 8);
        unsigned int q2 = (d.y >> 16) | ((d.z & 0xFFu) << 16);
        unsigned int q3 = d.z >> 8;
        acc[0] = fmaf(val, __builtin_bit_cast(float, q0 << 8), acc[0]);
        acc[1] = fmaf(val, __builtin_bit_cast(float, q1 << 8), acc[1]);
        acc[2] = fmaf(val, __builtin_bit_cast(float, q2 << 8), acc[2]);
        acc[3] = fmaf(val, __builtin_bit_cast(float, q3 << 8), acc[3]);
    }

    f32x4 bv = *(const f32x4*)&bias[lane * 4];
    ushort4v h, l;
    #pragma unroll
    for (int j = 0; j < 4; ++j) {
        float o = fmaxf(acc[j] + bv[j], 0.f);
        unsigned short hh = f2bf_rne(o);
        h[j] = hh;
        l[j] = f2bf_rne(o - bf2f(hh));
    }
    *(ushort4v*)&oh[(size_t)r * 256 + lane * 4] = h;
    *(ushort4v*)&ol[(size_t)r * 256 + lane * 4] = l;
}

// ---------------- SpMM F=128 (fp32 in) + fused bias/relu + final dense ----------------
__global__ __launch_bounds__(256)
void k_spmm128d(const int* __restrict__ rp, const int2* __restrict__ ev2,
                const float* __restrict__ in, const float* __restrict__ b3,
                const float* __restrict__ Wd, const float* __restrict__ bd,
                float* __restrict__ out, int N) {
    __shared__ float Ws[H4 * NCLASS];
    __shared__ float hrow[4][H4];
    {
        int i = threadIdx.x * 8;
        *(f32x4*)&Ws[i] = *(const f32x4*)&Wd[i];
        *(f32x4*)&Ws[i + 4] = *(const f32x4*)&Wd[i + 4];
    }
    __syncthreads();

    const int lane = threadIdx.x & 63;
    const int w = threadIdx.x >> 6;
    int r = __builtin_amdgcn_readfirstlane(blockIdx.x * 4 + w);
    if (r >= N) return;
    const int e0 = __builtin_amdgcn_readfirstlane(rp[r]);
    const int e1 = __builtin_amdgcn_readfirstlane(rp[r + 1]);
    float a0 = 0.f, a1 = 0.f;
    const float* base = in + (size_t)lane * 2;

    #pragma unroll 4
    for (int e = e0; e < e1; ++e) {
        int2 p = ev2[e];
        float2 x = *(const float2*)(base + (size_t)p.x * 128);
        float v = __builtin_bit_cast(float, p.y);
        a0 = fmaf(v, x.x, a0);
        a1 = fmaf(v, x.y, a1);
    }

    float2 hb;
    hb.x = fmaxf(a0 + b3[lane * 2 + 0], 0.f);
    hb.y = fmaxf(a1 + b3[lane * 2 + 1], 0.f);
    *(float2*)&hrow[w][lane * 2] = hb;

    const int c = lane & 15, q = lane >> 4;
    float s = 0.f;
    #pragma unroll
    for (int k = q * 32; k < q * 32 + 32; ++k)
        s = fmaf(hrow[w][k], Ws[k * NCLASS + c], s);
    s += __shfl_xor(s, 16);
    s += __shfl_xor(s, 32);
    if (lane < 16) out[(size_t)r * NCLASS + lane] = s + bd[lane];
}

extern "C" void kernel_launch(void* const* d_in, const int* in_sizes, int n_in,
                              void* d_out, int out_size, void* d_ws, size_t ws_size,
                              hipStream_t stream) {
    const float* x  = (const float*)d_in[0];
    const int*   er = (const int*)d_in[1];
    const int*   ec = (const int*)d_in[2];
    const float* ev = (const float*)d_in[3];
    const float* W1 = (const float*)d_in[4];
    const float* b1 = (const float*)d_in[5];
    const float* W2 = (const float*)d_in[6];
    const float* b2 = (const float*)d_in[7];
    const float* W3 = (const float*)d_in[8];
    const float* b3 = (const float*)d_in[9];
    const float* Wd = (const float*)d_in[10];
    const float* bd = (const float*)d_in[11];
    float* out = (float*)d_out;

    const int N = in_sizes[0] / NFEAT;
    const int E = in_sizes[1];

    char* w = (char*)d_ws;
    auto alloc = [&](size_t bytes) { char* p = w; w += (bytes + 255) & ~(size_t)255; return p; };
    float* C   = (float*)alloc((size_t)N * 256 * 4);
    unsigned int* C24 = (unsigned int*)alloc((size_t)N * 256 * 3);
    unsigned short* hh = (unsigned short*)alloc((size_t)N * 256 * 2);
    unsigned short* hl = (unsigned short*)alloc((size_t)N * 256 * 2);
    int* cnt  = (int*)alloc((size_t)N * 4);
    int* rp   = (int*)alloc((size_t)(N + 1) * 4);
    int* ofs  = (int*)alloc((size_t)N * 4);
    int2* ev2 = (int2*)alloc((size_t)E * 8);
    int* bsum = (int*)alloc(4096);
    unsigned short* W1h = (unsigned short*)alloc((size_t)NFEAT * H2 * 2);
    unsigned short* W1l = (unsigned short*)alloc((size_t)NFEAT * H2 * 2);
    unsigned short* W2h = (unsigned short*)alloc((size_t)H2 * H3 * 2);
    unsigned short* W2l = (unsigned short*)alloc((size_t)H2 * H3 * 2);
    unsigned short* W3h = (unsigned short*)alloc((size_t)H3 * H4 * 2);
    unsigned short* W3l = (unsigned short*)alloc((size_t)H3 * H4 * 2);

    const int nb = (N + 255) / 256;

    hipMemsetAsync(cnt, 0, (size_t)N * 4, stream);
    k_hist<<<1024, 256, 0, stream>>>(er, cnt, E);
    k_scan1<<<nb, 256, 0, stream>>>(cnt, rp, bsum, N);
    k_scan2<<<1, 512, 0, stream>>>(bsum, nb);
    k_scan3<<<nb, 256, 0, stream>>>(rp, ofs, bsum, cnt, N);
    k_scatter<<<1024, 256, 0, stream>>>(er, ec, ev, ofs, ev2, E);

    k_split_w<<<(NFEAT * H2 + 255) / 256, 256, 0, stream>>>(W1, W1h, W1l, NFEAT, H2);
    k_split_w<<<(H2 * H3 + 255) / 256, 256, 0, stream>>>(W2, W2h, W2l, H2, H3);
    k_split_w<<<(H3 * H4 + 255) / 256, 256, 0, stream>>>(W3, W3h, W3l, H3, H4);

    const int rgrid = (N + 63) / 64;
    const int sgrid = (N + 3) / 4;
    const long ngroup = (long)N * 256 / 4;
    const int pgrid = (int)((ngroup + 255) / 256);

    k_gemm1w<<<rgrid, 256, 0, stream>>>(x, W1h, W1l, C, N);
    k_pack24<<<pgrid, 256, 0, stream>>>(C, C24, ngroup);
    k_spmm256p<<<sgrid, 256, 0, stream>>>(rp, ev2, C24, b1, hh, hl, N);

    k_gemm_bt<H2, 4><<<rgrid, 256, 0, stream>>>(hh, hl, W2h, W2l, C, N);
    k_pack24<<<pgrid, 256, 0, stream>>>(C, C24, ngroup);
    k_spmm256p<<<sgrid, 256, 0, stream>>>(rp, ev2, C24, b2, hh, hl, N);

    k_gemm_bt<H3, 2><<<rgrid, 256, 0, stream>>>(hh, hl, W3h, W3l, C, N);
    k_spmm128d<<<sgrid, 256, 0, stream>>>(rp, ev2, C, b3, Wd, bd, out, N);
}